// Round 5
// baseline (671.519 us; speedup 1.0000x reference)
//
#include <hip/hip_runtime.h>
#include <hip/hip_bf16.h>

#define B_ 8
#define C_ 128
#define H_ 128
#define W_ 128

typedef __bf16 bf16;
typedef __bf16 bf16x8 __attribute__((ext_vector_type(8)));
typedef __bf16 bf16x4 __attribute__((ext_vector_type(4)));
typedef float f32x4 __attribute__((ext_vector_type(4)));

#define GLD_LDS16(gsrc, ldsdst)                                                              \
    __builtin_amdgcn_global_load_lds((const __attribute__((address_space(1))) void*)(gsrc),  \
                                     (__attribute__((address_space(3))) void*)(ldsdst),      \
                                     16, 0, 0)

#define WAITVM0 asm volatile("s_waitcnt vmcnt(0)" ::: "memory")

// ---------------------------------------------------------------------------
// Weight prep
// ---------------------------------------------------------------------------
__global__ void wprep1_kernel(const float* __restrict__ w, bf16* __restrict__ o) {
    int i = blockIdx.x * 256 + threadIdx.x;
    if (i >= 256 * 128 * 9) return;
    int tap = i % 9, cc = (i / 9) % 128, co = i / (9 * 128);
    o[(tap * 256 + co) * 128 + cc] = (bf16)w[i];
}

__global__ void wprepE_kernel(const float* __restrict__ w, bf16* __restrict__ o) {
    int i = blockIdx.x * 256 + threadIdx.x;
    if (i >= 3 * 128 * 128 * 9) return;
    int tap = i % 9, cc = (i / 9) % 128, co = (i / (9 * 128)) % 128, e = i / (9 * 128 * 128);
    o[(((e * 9 + tap) * 128 + co) * 128) + cc] = (bf16)w[i];
}

__global__ void wprep3_kernel(const float* __restrict__ w, bf16* __restrict__ o) {
    int i = blockIdx.x * 256 + threadIdx.x;
    if (i >= 3 * 128 * 128) return;
    o[i] = (bf16)w[i];
}

// ---------------------------------------------------------------------------
// |x| NCHW fp32 -> NHWC bf16
// ---------------------------------------------------------------------------
__global__ __launch_bounds__(256) void xpose_kernel(const float* __restrict__ x,
                                                    bf16* __restrict__ xa)
{
    const int cblk = blockIdx.x, h = blockIdx.y, b = blockIdx.z;
    const int t = threadIdx.x;
    __shared__ float sx[32][133];
    for (int i = t; i < 32 * 128; i += 256) {
        int c = i >> 7, w = i & 127;
        sx[c][w] = fabsf(x[((size_t)(b * C_ + cblk * 32 + c) * H_ + h) * W_ + w]);
    }
    __syncthreads();
    for (int g = t; g < 512; g += 256) {
        int w = g >> 2, slot = g & 3;
        bf16x8 v;
#pragma unroll
        for (int j = 0; j < 8; j++) v[j] = (bf16)sx[slot * 8 + j][w];
        *(bf16x8*)&xa[((size_t)(b * H_ + h) * W_ + w) * C_ + cblk * 32 + slot * 8] = v;
    }
}

// ---------------------------------------------------------------------------
// Full-tile staging: logical [4 halo rows][66 w][128 cc] bf16 per tensor.
// granule g = (row*66 + w)*16 + sp (16B = 8cc), logical slot = sp ^ (w&15).
// 4224 granules = 67584 B. Staged in 66 wave-rounds (wave-uniform base).
// B-frag read byte = (((row_h*66+wl)*16) + ((cb*4+l4)^(wl&15)))*16 :
// bank-group = slot%8 spreads across lanes via the XOR -> ~2-way (free).
// ---------------------------------------------------------------------------
__device__ __forceinline__ void stage_full(const bf16* __restrict__ base,
    const bf16* __restrict__ zbuf, char* dst,
    int lane, int ww, int b, int h0, int w0)
{
    for (int r = ww; r < 66; r += 8) {
        int g = r * 64 + lane;
        int row = g / 1056;              // 1056 = 66*16
        int rem = g - row * 1056;
        int w = rem >> 4, sp = rem & 15;
        int slot = sp ^ (w & 15);
        int hh = h0 + row - 1, gw = w0 + w - 1;
        const bf16* src = zbuf;
        if ((unsigned)hh < 128u && (unsigned)gw < 128u)
            src = base + ((size_t)(b * H_ + hh) * W_ + gw) * C_ + slot * 8;
        GLD_LDS16(src, dst + (size_t)r * 1024);
    }
}

// ---------------------------------------------------------------------------
// K1: conv3x3(|x|)+bias -> xh/kk + gating sums. Full-LDS tile, barrier-free
// main loop. 512 thr; tile 2 rows x 64 px x 256 co; wave = 64co x 64px.
// ---------------------------------------------------------------------------
__global__ __launch_bounds__(512, 2) void conv1_kernel(
    const bf16* __restrict__ xa, const bf16* __restrict__ wT1,
    const float* __restrict__ bias,
    bf16* __restrict__ xh, bf16* __restrict__ kk,
    float* __restrict__ meansum, const bf16* __restrict__ zbuf)
{
    const int bid = blockIdx.x;
    const int b = bid & 7, rp = (bid >> 3) & 63, pxh = bid >> 9;
    const int h0 = rp * 2, w0 = pxh * 64;
    const int t = threadIdx.x, lane = t & 63, ww = t >> 6;
    const int l15 = lane & 15, l4 = lane >> 4;
    const int rowL = ww & 1, co0 = (ww >> 1) * 64;
    __shared__ char sm[67584];

    f32x4 acc[4][4];
#pragma unroll
    for (int mf = 0; mf < 4; mf++)
#pragma unroll
        for (int nf = 0; nf < 4; nf++) acc[mf][nf] = (f32x4){0.f, 0.f, 0.f, 0.f};

    stage_full(xa, zbuf, sm, lane, ww, b, h0, w0);
    WAITVM0;
    __syncthreads();

#pragma unroll 1
    for (int cb = 0; cb < 4; cb++) {
#pragma unroll 1
        for (int dy = 0; dy < 3; dy++) {
            const int row_h = rowL + dy;
#pragma unroll
            for (int dx = 0; dx < 3; dx++) {
                const int tap = dy * 3 + dx;
                bf16x8 af[4];
#pragma unroll
                for (int mf = 0; mf < 4; mf++)
                    af[mf] = *(const bf16x8*)&wT1[(size_t)(tap * 256 + co0 + mf * 16 + l15) * 128 + cb * 32 + l4 * 8];
                bf16x8 bv[4];
#pragma unroll
                for (int nf = 0; nf < 4; nf++) {
                    int wl = nf * 16 + l15 + dx;
                    int byt = (((row_h * 66 + wl) << 4) + ((cb * 4 + l4) ^ (wl & 15))) << 4;
                    bv[nf] = *(const bf16x8*)(sm + byt);
                }
#pragma unroll
                for (int mf = 0; mf < 4; mf++)
#pragma unroll
                    for (int nf = 0; nf < 4; nf++)
                        acc[mf][nf] = __builtin_amdgcn_mfma_f32_16x16x32_bf16(af[mf], bv[nf], acc[mf][nf], 0, 0, 0);
            }
        }
    }

    const int hG = h0 + rowL;
    float bvv[4][4];
#pragma unroll
    for (int mf = 0; mf < 4; mf++)
#pragma unroll
        for (int r = 0; r < 4; r++) bvv[mf][r] = bias[co0 + mf * 16 + 4 * l4 + r];

    bf16* dst = (co0 < 128) ? xh : kk;
    const int cod = co0 & 127;
#pragma unroll
    for (int mf = 0; mf < 4; mf++) {
#pragma unroll
        for (int nf = 0; nf < 4; nf++) {
            int w = w0 + nf * 16 + l15;
            bf16x4 v;
#pragma unroll
            for (int r = 0; r < 4; r++) v[r] = (bf16)(acc[mf][nf][r] + bvv[mf][r]);
            *(bf16x4*)&dst[((size_t)(b * H_ + hG) * W_ + w) * C_ + cod + mf * 16 + 4 * l4] = v;
        }
        if (co0 < 128) {
#pragma unroll
            for (int r = 0; r < 4; r++) {
                float s = 4.f * bvv[mf][r];
#pragma unroll
                for (int nf = 0; nf < 4; nf++) s += acc[mf][nf][r];
                s += __shfl_xor(s, 1, 64);
                s += __shfl_xor(s, 2, 64);
                s += __shfl_xor(s, 4, 64);
                s += __shfl_xor(s, 8, 64);
                if (l15 == 0)
                    atomicAdd(&meansum[b * 128 + co0 + mf * 16 + 4 * l4 + r], s);
            }
        }
    }
}

// ---------------------------------------------------------------------------
// K2: gating (top-2 of 3; drop argmin, ties drop larger index)
// ---------------------------------------------------------------------------
__global__ void gate_kernel(const float* __restrict__ meansum,
                            const float* __restrict__ gw,
                            float* __restrict__ gate)
{
    int b = threadIdx.x;
    if (b >= 8) return;
    float l[3];
    for (int e = 0; e < 3; e++) {
        float s = 0.f;
        for (int c = 0; c < 128; c++) s += meansum[b * 128 + c] * gw[e * 128 + c];
        l[e] = s * (1.0f / 16384.0f);
    }
    float m = fmaxf(l[0], fmaxf(l[1], l[2]));
    float p0 = expf(l[0] - m), p1 = expf(l[1] - m), p2 = expf(l[2] - m);
    float s = p0 + p1 + p2;
    float w[3] = { p0 / s, p1 / s, p2 / s };
    int dm = 0;
    if (w[1] <= w[0]) dm = 1;
    if (w[2] <= w[dm]) dm = 2;
    for (int e = 0; e < 3; e++) gate[b * 3 + e] = (e == dm) ? 0.f : w[e];
}

// ---------------------------------------------------------------------------
// K3a/K3b: fem_b(0) -> [C][9-region] map
// ---------------------------------------------------------------------------
__global__ __launch_bounds__(128) void out2a_kernel(
    const float* __restrict__ c1b,
    const float* __restrict__ ew1, const float* __restrict__ eb1,
    const float* __restrict__ ew2, const float* __restrict__ eb2,
    float* __restrict__ sprod)
{
    const int e = blockIdx.x >> 7, c = blockIdx.x & 127;
    const int t = threadIdx.x;
    float xv = c1b[t], kv = c1b[128 + t];
    const float* w1 = ew1 + ((size_t)(e * 128 + c) * 128 + t) * 9;
    const float* w2 = ew2 + ((size_t)(e * 128 + c) * 128 + t) * 9;
    __shared__ float rA[9][128], rB[9][128];
#pragma unroll
    for (int tp = 0; tp < 9; tp++) { rA[tp][t] = xv * w1[tp]; rB[tp][t] = kv * w2[tp]; }
    __syncthreads();
    for (int s = 64; s > 0; s >>= 1) {
        if (t < s)
#pragma unroll
            for (int tp = 0; tp < 9; tp++) { rA[tp][t] += rA[tp][t + s]; rB[tp][t] += rB[tp][t + s]; }
        __syncthreads();
    }
    if (t < 9) {
        int rcl = t / 3, ccl = t % 3;
        float av = eb1[e * 128 + c], bv = eb2[e * 128 + c];
#pragma unroll
        for (int i = 0; i < 3; i++)
#pragma unroll
            for (int j = 0; j < 3; j++) {
                bool iok = (rcl == 1) || (rcl == 0 && i >= 1) || (rcl == 2 && i <= 1);
                bool jok = (ccl == 1) || (ccl == 0 && j >= 1) || (ccl == 2 && j <= 1);
                if (iok && jok) { av += rA[i * 3 + j][0]; bv += rB[i * 3 + j][0]; }
            }
        sprod[(size_t)(e * 128 + c) * 9 + t] = av * bv;
    }
}

__global__ __launch_bounds__(128) void out2b_kernel(
    const float* __restrict__ c1b, const float* __restrict__ gw,
    const float* __restrict__ sprod, const float* __restrict__ ew3,
    const float* __restrict__ eb3, float* __restrict__ out2map)
{
    const int c = blockIdx.x;
    const int t = threadIdx.x;
    __shared__ float red[27][128];
#pragma unroll
    for (int e = 0; e < 3; e++) {
        float wv = ew3[(size_t)(e * 128 + c) * 128 + t];
#pragma unroll
        for (int r = 0; r < 9; r++) red[e * 9 + r][t] = wv * sprod[(size_t)(e * 128 + t) * 9 + r];
    }
    __syncthreads();
    for (int s = 64; s > 0; s >>= 1) {
        if (t < s)
#pragma unroll
            for (int q = 0; q < 27; q++) red[q][t] += red[q][t + s];
        __syncthreads();
    }
    __shared__ float lsh[3];
    if (t < 3) {
        float s = 0.f;
        for (int cc = 0; cc < 128; cc++) s += c1b[cc] * gw[t * 128 + cc];
        lsh[t] = s;
    }
    __syncthreads();
    if (t == 0) {
        float l0 = lsh[0], l1 = lsh[1], l2 = lsh[2];
        float m = fmaxf(l0, fmaxf(l1, l2));
        float p0 = expf(l0 - m), p1 = expf(l1 - m), p2 = expf(l2 - m);
        float ssum = p0 + p1 + p2;
        float wv[3] = { p0 / ssum, p1 / ssum, p2 / ssum };
        int dm = 0;
        if (wv[1] <= wv[0]) dm = 1;
        if (wv[2] <= wv[dm]) dm = 2;
        wv[dm] = 0.f;
        for (int r = 0; r < 9; r++) {
            float o = c1b[c];
            for (int e = 0; e < 3; e++)
                o += wv[e] * (red[e * 9 + r][0] + eb3[e * 128 + c]);
            out2map[c * 9 + r] = o;
        }
    }
}

// ---------------------------------------------------------------------------
// K4: both experts, full-LDS staging (X 66KB + K 66KB + P-half 16KB), one
// stage wait, barrier-free main MFMA loop, half-P 1x1 tail, single out write.
// ---------------------------------------------------------------------------
__global__ __launch_bounds__(512, 2) void expert_kernel(
    const bf16* __restrict__ xhp, const bf16* __restrict__ kkp,
    const bf16* __restrict__ we1, const float* __restrict__ eb1,
    const bf16* __restrict__ we2, const float* __restrict__ eb2,
    const bf16* __restrict__ w3, const float* __restrict__ eb3,
    const float* __restrict__ gate, const float* __restrict__ o2map,
    const float* __restrict__ x, float* __restrict__ out,
    const bf16* __restrict__ zbuf)
{
    const int bid = blockIdx.x;
    const int b = bid & 7, rp = (bid >> 3) & 63, pxh = bid >> 9;
    const int h0 = rp * 2, w0 = pxh * 64;
    const int t = threadIdx.x, lane = t & 63, ww = t >> 6;
    const int l15 = lane & 15, l4 = lane >> 4;
    const int rowL = ww & 1, co0 = (ww >> 1) * 32;
    __shared__ char sm[151552];
    char* X = sm;
    char* K = sm + 67584;
    char* PB = sm + 135168;

    float ga0 = gate[b * 3 + 0], ga1 = gate[b * 3 + 1], ga2 = gate[b * 3 + 2];
    int e0, e1; float w_e0, w_e1;
    if (ga0 > 0.f) { e0 = 0; w_e0 = ga0; if (ga1 > 0.f) { e1 = 1; w_e1 = ga1; } else { e1 = 2; w_e1 = ga2; } }
    else           { e0 = 1; w_e0 = ga1; e1 = 2; w_e1 = ga2; }

    stage_full(xhp, zbuf, X, lane, ww, b, h0, w0);
    stage_full(kkp, zbuf, K, lane, ww, b, h0, w0);

    f32x4 aa[2][2][4], ab[2][2][4];   // [expert][mf co][nf px]
#pragma unroll
    for (int pe = 0; pe < 2; pe++)
#pragma unroll
        for (int mf = 0; mf < 2; mf++)
#pragma unroll
            for (int nf = 0; nf < 4; nf++) {
                aa[pe][mf][nf] = (f32x4){0.f, 0.f, 0.f, 0.f};
                ab[pe][mf][nf] = (f32x4){0.f, 0.f, 0.f, 0.f};
            }

    WAITVM0;
    __syncthreads();

    // ---- barrier-free main conv loop: both experts, both convs ----
#pragma unroll 1
    for (int cb = 0; cb < 4; cb++) {
#pragma unroll 1
        for (int dy = 0; dy < 3; dy++) {
            const int row_h = rowL + dy;
#pragma unroll
            for (int dx = 0; dx < 3; dx++) {
                const int tap = dy * 3 + dx;
                int bofs[4];
#pragma unroll
                for (int nf = 0; nf < 4; nf++) {
                    int wl = nf * 16 + l15 + dx;
                    bofs[nf] = (((row_h * 66 + wl) << 4) + ((cb * 4 + l4) ^ (wl & 15))) << 4;
                }
                bf16x8 a10, a11, a20, a21, a10b, a11b, a20b, a21b;
                {
                    size_t wbase = (size_t)(cb * 32 + l4 * 8);
                    const bf16* p0 = we1 + (size_t)((e0 * 9 + tap) * 128 + co0 + l15) * 128 + wbase;
                    const bf16* p1 = we1 + (size_t)((e1 * 9 + tap) * 128 + co0 + l15) * 128 + wbase;
                    const bf16* q0 = we2 + (size_t)((e0 * 9 + tap) * 128 + co0 + l15) * 128 + wbase;
                    const bf16* q1 = we2 + (size_t)((e1 * 9 + tap) * 128 + co0 + l15) * 128 + wbase;
                    a10  = *(const bf16x8*)p0;        a10b = *(const bf16x8*)(p0 + 16 * 128);
                    a11  = *(const bf16x8*)p1;        a11b = *(const bf16x8*)(p1 + 16 * 128);
                    a20  = *(const bf16x8*)q0;        a20b = *(const bf16x8*)(q0 + 16 * 128);
                    a21  = *(const bf16x8*)q1;        a21b = *(const bf16x8*)(q1 + 16 * 128);
                }
#pragma unroll
                for (int nf = 0; nf < 4; nf++) {
                    bf16x8 bx = *(const bf16x8*)(X + bofs[nf]);
                    aa[0][0][nf] = __builtin_amdgcn_mfma_f32_16x16x32_bf16(a10, bx, aa[0][0][nf], 0, 0, 0);
                    aa[0][1][nf] = __builtin_amdgcn_mfma_f32_16x16x32_bf16(a10b, bx, aa[0][1][nf], 0, 0, 0);
                    aa[1][0][nf] = __builtin_amdgcn_mfma_f32_16x16x32_bf16(a11, bx, aa[1][0][nf], 0, 0, 0);
                    aa[1][1][nf] = __builtin_amdgcn_mfma_f32_16x16x32_bf16(a11b, bx, aa[1][1][nf], 0, 0, 0);
                }
#pragma unroll
                for (int nf = 0; nf < 4; nf++) {
                    bf16x8 bk = *(const bf16x8*)(K + bofs[nf]);
                    ab[0][0][nf] = __builtin_amdgcn_mfma_f32_16x16x32_bf16(a20, bk, ab[0][0][nf], 0, 0, 0);
                    ab[0][1][nf] = __builtin_amdgcn_mfma_f32_16x16x32_bf16(a20b, bk, ab[0][1][nf], 0, 0, 0);
                    ab[1][0][nf] = __builtin_amdgcn_mfma_f32_16x16x32_bf16(a21, bk, ab[1][0][nf], 0, 0, 0);
                    ab[1][1][nf] = __builtin_amdgcn_mfma_f32_16x16x32_bf16(a21b, bk, ab[1][1][nf], 0, 0, 0);
                }
            }
        }
    }

    // ---- tail: per half-row, per expert: P -> LDS, 1x1 GEMM, one out write ----
#pragma unroll 1
    for (int half = 0; half < 2; half++) {
        f32x4 eoA[2][2], eoB[2][2];   // [mf][nf2]
#pragma unroll
        for (int mf = 0; mf < 2; mf++)
#pragma unroll
            for (int nf = 0; nf < 2; nf++) {
                eoA[mf][nf] = (f32x4){0.f, 0.f, 0.f, 0.f};
                eoB[mf][nf] = (f32x4){0.f, 0.f, 0.f, 0.f};
            }
        const int px0q = (ww & 1) * 32;

#pragma unroll 1
        for (int pe = 0; pe < 2; pe++) {
            const int e = pe ? e1 : e0;
            // P-write: waves owning this row
            if (rowL == half) {
#pragma unroll
                for (int mf = 0; mf < 2; mf++) {
                    int ccb = co0 + mf * 16 + 4 * l4;
                    float b1v[4], b2v[4];
#pragma unroll
                    for (int r = 0; r < 4; r++) {
                        b1v[r] = eb1[e * 128 + ccb + r];
                        b2v[r] = eb2[e * 128 + ccb + r];
                    }
#pragma unroll
                    for (int nf = 0; nf < 4; nf++) {
                        int px = nf * 16 + l15;
                        bf16x4 pv;
#pragma unroll
                        for (int r = 0; r < 4; r++)
                            pv[r] = (bf16)((aa[pe][mf][nf][r] + b1v[r]) * (ab[pe][mf][nf][r] + b2v[r]));
                        int byt = ((px << 4) + ((ccb >> 3) ^ (px & 15))) * 16 + (ccb & 7) * 2;
                        *(bf16x4*)(PB + byt) = pv;
                    }
                }
            }
            __syncthreads();
            // 1x1 GEMM on this half: all 8 waves, wave = 32co x 32px
#pragma unroll 1
            for (int ks = 0; ks < 4; ks++) {
                bf16x8 a3[2];
#pragma unroll
                for (int mf = 0; mf < 2; mf++)
                    a3[mf] = *(const bf16x8*)&w3[(size_t)(e * 128 + co0 + mf * 16 + l15) * 128 + ks * 32 + l4 * 8];
#pragma unroll
                for (int nf = 0; nf < 2; nf++) {
                    int px = px0q + nf * 16 + l15;
                    int byt = ((px << 4) + ((ks * 4 + l4) ^ (px & 15))) << 4;
                    bf16x8 bp = *(const bf16x8*)(PB + byt);
#pragma unroll
                    for (int mf = 0; mf < 2; mf++) {
                        if (pe == 0)
                            eoA[mf][nf] = __builtin_amdgcn_mfma_f32_16x16x32_bf16(a3[mf], bp, eoA[mf][nf], 0, 0, 0);
                        else
                            eoB[mf][nf] = __builtin_amdgcn_mfma_f32_16x16x32_bf16(a3[mf], bp, eoB[mf][nf], 0, 0, 0);
                    }
                }
            }
            __syncthreads();   // P reused by next expert / next half
        }

        // epilogue for this half: out = xh + x + o2map + we0*eoA + we1*eoB
        const int h = h0 + half;
        const int rcl = (h == 0) ? 0 : ((h == 127) ? 2 : 1);
#pragma unroll
        for (int mf = 0; mf < 2; mf++) {
            int cbase = co0 + mf * 16 + 4 * l4;
            float b30[4], b31[4];
#pragma unroll
            for (int r = 0; r < 4; r++) {
                b30[r] = eb3[e0 * 128 + cbase + r];
                b31[r] = eb3[e1 * 128 + cbase + r];
            }
#pragma unroll
            for (int nf = 0; nf < 2; nf++) {
                int px = px0q + nf * 16 + l15;
                int w = w0 + px;
                // xh value from staged X tile (row_h = half+1, wl = px+1)
                int wl = px + 1;
                int xbyt = (((half + 1) * 66 + wl) * 16 + ((cbase >> 3) ^ (wl & 15))) * 16 + (cbase & 7) * 2;
                bf16x4 xv = *(const bf16x4*)(X + xbyt);
                int ccl = (w == 0) ? 0 : ((w == 127) ? 2 : 1);
#pragma unroll
                for (int r = 0; r < 4; r++) {
                    size_t gi = ((size_t)(b * C_ + cbase + r) * H_ + h) * W_ + w;
                    out[gi] = (float)xv[r] + x[gi] + o2map[(cbase + r) * 9 + rcl * 3 + ccl]
                            + w_e0 * (eoA[mf][nf][r] + b30[r])
                            + w_e1 * (eoB[mf][nf][r] + b31[r]);
                }
            }
        }
    }
}

// ---------------------------------------------------------------------------
extern "C" void kernel_launch(void* const* d_in, const int* in_sizes, int n_in,
                              void* d_out, int out_size, void* d_ws, size_t ws_size,
                              hipStream_t stream)
{
    const float* x      = (const float*)d_in[0];
    const float* a_c1w  = (const float*)d_in[1];
    const float* a_c1b  = (const float*)d_in[2];
    const float* a_gw   = (const float*)d_in[3];
    const float* a_ew1  = (const float*)d_in[4];
    const float* a_eb1  = (const float*)d_in[5];
    const float* a_ew2  = (const float*)d_in[6];
    const float* a_eb2  = (const float*)d_in[7];
    const float* a_ew3  = (const float*)d_in[8];
    const float* a_eb3  = (const float*)d_in[9];
    const float* b_c1b  = (const float*)d_in[11];
    const float* b_gw   = (const float*)d_in[12];
    const float* b_ew1  = (const float*)d_in[13];
    const float* b_eb1  = (const float*)d_in[14];
    const float* b_ew2  = (const float*)d_in[15];
    const float* b_eb2  = (const float*)d_in[16];
    const float* b_ew3  = (const float*)d_in[17];
    const float* b_eb3  = (const float*)d_in[18];
    float* out = (float*)d_out;

    char* ws = (char*)d_ws;
    bf16*  xh      = (bf16*)(ws);                      // 33554432 B
    bf16*  kk      = (bf16*)(ws + 33554432);           // 33554432 B
    bf16*  wT1     = (bf16*)(ws + 67108864);           // 589824 B
    bf16*  wTe1    = (bf16*)(ws + 67698688);           // 884736 B
    bf16*  wTe2    = (bf16*)(ws + 68583424);           // 884736 B
    bf16*  wT3     = (bf16*)(ws + 69468160);           // 98304 B
    float* meansum = (float*)(ws + 69566464);          // 4096 B
    float* gate    = (float*)(ws + 69570560);          // 128 B
    float* o2map   = (float*)(ws + 69570688);          // 4608 B
    bf16*  zbuf    = (bf16*)(ws + 69575296);           // 256 B
    float* sprod   = (float*)(ws + 69575552);          // 13824 B

    bf16* xa = (bf16*)d_out;   // |x| NHWC bf16 scratch (overwritten last)

    hipMemsetAsync(ws + 69566464, 0, 4096, stream);        // meansum
    hipMemsetAsync(ws + 69575296, 0, 256, stream);         // zero buffer

    wprep1_kernel<<<(256 * 128 * 9 + 255) / 256, 256, 0, stream>>>(a_c1w, wT1);
    wprepE_kernel<<<(3 * 128 * 128 * 9 + 255) / 256, 256, 0, stream>>>(a_ew1, wTe1);
    wprepE_kernel<<<(3 * 128 * 128 * 9 + 255) / 256, 256, 0, stream>>>(a_ew2, wTe2);
    wprep3_kernel<<<(3 * 128 * 128 + 255) / 256, 256, 0, stream>>>(a_ew3, wT3);

    xpose_kernel<<<dim3(4, 128, 8), 256, 0, stream>>>(x, xa);

    conv1_kernel<<<1024, 512, 0, stream>>>(xa, wT1, a_c1b, xh, kk, meansum, zbuf);

    gate_kernel<<<1, 64, 0, stream>>>(meansum, a_gw, gate);
    out2a_kernel<<<384, 128, 0, stream>>>(b_c1b, b_ew1, b_eb1, b_ew2, b_eb2, sprod);
    out2b_kernel<<<128, 128, 0, stream>>>(b_c1b, b_gw, sprod, b_ew3, b_eb3, o2map);

    expert_kernel<<<1024, 512, 0, stream>>>(
        xh, kk, wTe1, a_eb1, wTe2, a_eb2, wT3, a_eb3, gate, o2map, x, out, zbuf);
}

// Round 6
// 538.519 us; speedup vs baseline: 1.2470x; 1.2470x over previous
//
#include <hip/hip_runtime.h>
#include <hip/hip_bf16.h>

#define B_ 8
#define C_ 128
#define H_ 128
#define W_ 128

typedef __bf16 bf16;
typedef __bf16 bf16x8 __attribute__((ext_vector_type(8)));
typedef __bf16 bf16x4 __attribute__((ext_vector_type(4)));
typedef float f32x4 __attribute__((ext_vector_type(4)));

#define GLD_LDS16(gsrc, ldsdst)                                                              \
    __builtin_amdgcn_global_load_lds((const __attribute__((address_space(1))) void*)(gsrc),  \
                                     (__attribute__((address_space(3))) void*)(ldsdst),      \
                                     16, 0, 0)

#define WAITVM0 asm volatile("s_waitcnt vmcnt(0)" ::: "memory")
#define WAITVM3 asm volatile("s_waitcnt vmcnt(3)" ::: "memory")
#define WAITVM6 asm volatile("s_waitcnt vmcnt(6)" ::: "memory")

__device__ __forceinline__ void barrier_raw() {
    __builtin_amdgcn_sched_barrier(0);
    __builtin_amdgcn_s_barrier();
    __builtin_amdgcn_sched_barrier(0);
}

// ---------------------------------------------------------------------------
// Weight prep
// ---------------------------------------------------------------------------
__global__ void wprep1_kernel(const float* __restrict__ w, bf16* __restrict__ o) {
    int i = blockIdx.x * 256 + threadIdx.x;
    if (i >= 256 * 128 * 9) return;
    int tap = i % 9, cc = (i / 9) % 128, co = i / (9 * 128);
    o[(tap * 256 + co) * 128 + cc] = (bf16)w[i];
}

__global__ void wprepE_kernel(const float* __restrict__ w, bf16* __restrict__ o) {
    int i = blockIdx.x * 256 + threadIdx.x;
    if (i >= 3 * 128 * 128 * 9) return;
    int tap = i % 9, cc = (i / 9) % 128, co = (i / (9 * 128)) % 128, e = i / (9 * 128 * 128);
    o[(((e * 9 + tap) * 128 + co) * 128) + cc] = (bf16)w[i];
}

__global__ void wprep3_kernel(const float* __restrict__ w, bf16* __restrict__ o) {
    int i = blockIdx.x * 256 + threadIdx.x;
    if (i >= 3 * 128 * 128) return;
    o[i] = (bf16)w[i];
}

// ---------------------------------------------------------------------------
// |x| NCHW fp32 -> NHWC bf16
// ---------------------------------------------------------------------------
__global__ __launch_bounds__(256) void xpose_kernel(const float* __restrict__ x,
                                                    bf16* __restrict__ xa)
{
    const int cblk = blockIdx.x, h = blockIdx.y, b = blockIdx.z;
    const int t = threadIdx.x;
    __shared__ float sx[32][133];
    for (int i = t; i < 32 * 128; i += 256) {
        int c = i >> 7, w = i & 127;
        sx[c][w] = fabsf(x[((size_t)(b * C_ + cblk * 32 + c) * H_ + h) * W_ + w]);
    }
    __syncthreads();
    for (int g = t; g < 512; g += 256) {
        int w = g >> 2, slot = g & 3;
        bf16x8 v;
#pragma unroll
        for (int j = 0; j < 8; j++) v[j] = (bf16)sx[slot * 8 + j][w];
        *(bf16x8*)&xa[((size_t)(b * H_ + h) * W_ + w) * C_ + cblk * 32 + slot * 8] = v;
    }
}

// ---------------------------------------------------------------------------
// Staging tile (R4-proven): logical [4 halo rows][66 w][32 cc] bf16.
// granule g = row*272 + w*4 + sp, slot = sp ^ ((w>>1)&3). 1088 granules.
// Every wave issues EXACTLY 3 global_load_lds per stage (waves 1-7's third
// issue goes to a dump area) so vmcnt immediates are wave-uniform.
// ---------------------------------------------------------------------------
__device__ __forceinline__ void stage_tile(const bf16* __restrict__ base,
    const bf16* __restrict__ zbuf, char* dst, char* dump,
    int t, int ww, int b, int h0, int w0, int cb)
{
#pragma unroll
    for (int k = 0; k < 3; k++) {
        int g = t + k * 512;
        char* d = dst + (size_t)((t & 448) + k * 512) * 16;
        bool real = (k < 2) || (ww == 0);
        if (k == 2 && ww != 0) d = dump;
        const bf16* src = zbuf;
        if (real) {
            int row = g / 272, rem = g - row * 272;
            int w = rem >> 2, sp = rem & 3;
            int slot = sp ^ ((w >> 1) & 3);
            int hh = h0 + row - 1, gw = w0 + w - 1;
            if (rem < 264 && (unsigned)hh < 128u && (unsigned)gw < 128u)
                src = base + ((size_t)(b * H_ + hh) * W_ + gw) * C_ + cb * 32 + slot * 8;
        }
        GLD_LDS16(src, d);
    }
}

// ---------------------------------------------------------------------------
// K1: conv3x3(|x|)+bias -> xh/kk + gating sums.
// Double-buffered staging; one vmcnt + barrier per cb; 144-MFMA regions.
// ---------------------------------------------------------------------------
__global__ __launch_bounds__(512, 2) void conv1_kernel(
    const bf16* __restrict__ xa, const bf16* __restrict__ wT1,
    const float* __restrict__ bias,
    bf16* __restrict__ xh, bf16* __restrict__ kk,
    float* __restrict__ meansum, const bf16* __restrict__ zbuf)
{
    const int bid = blockIdx.x;
    const int b = bid & 7, rp = (bid >> 3) & 63, pxh = bid >> 9;
    const int h0 = rp * 2, w0 = pxh * 64;
    const int t = threadIdx.x, lane = t & 63, ww = t >> 6;
    const int l15 = lane & 15, l4 = lane >> 4;
    const int rowL = ww & 1, co0 = (ww >> 1) * 64;
    __shared__ char sm[35840];
    char* B0 = sm;
    char* B1 = sm + 17408;
    char* dump = sm + 34816;

    f32x4 acc[4][4];
#pragma unroll
    for (int mf = 0; mf < 4; mf++)
#pragma unroll
        for (int nf = 0; nf < 4; nf++) acc[mf][nf] = (f32x4){0.f, 0.f, 0.f, 0.f};

    stage_tile(xa, zbuf, B0, dump, t, ww, b, h0, w0, 0);
    stage_tile(xa, zbuf, B1, dump, t, ww, b, h0, w0, 1);

#pragma unroll
    for (int cb = 0; cb < 4; cb++) {
        if (cb < 3) { WAITVM3; } else { WAITVM0; }
        barrier_raw();
        const char* buf = (cb & 1) ? B1 : B0;
#pragma unroll 1
        for (int dy = 0; dy < 3; dy++) {
            const int row_h = rowL + dy;
#pragma unroll
            for (int dx = 0; dx < 3; dx++) {
                const int tap = dy * 3 + dx;
                bf16x8 af[4];
#pragma unroll
                for (int mf = 0; mf < 4; mf++)
                    af[mf] = *(const bf16x8*)&wT1[(size_t)(tap * 256 + co0 + mf * 16 + l15) * 128 + cb * 32 + l4 * 8];
                bf16x8 bv[4];
#pragma unroll
                for (int nf = 0; nf < 4; nf++) {
                    int wl = nf * 16 + l15 + dx;
                    int byt = (row_h * 272 + wl * 4 + (l4 ^ ((wl >> 1) & 3))) * 16;
                    bv[nf] = *(const bf16x8*)(buf + byt);
                }
#pragma unroll
                for (int mf = 0; mf < 4; mf++)
#pragma unroll
                    for (int nf = 0; nf < 4; nf++)
                        acc[mf][nf] = __builtin_amdgcn_mfma_f32_16x16x32_bf16(af[mf], bv[nf], acc[mf][nf], 0, 0, 0);
            }
        }
        if (cb < 2) {
            barrier_raw();
            stage_tile(xa, zbuf, (cb & 1) ? B1 : B0, dump, t, ww, b, h0, w0, cb + 2);
        }
    }

    const int hG = h0 + rowL;
    float bvv[4][4];
#pragma unroll
    for (int mf = 0; mf < 4; mf++)
#pragma unroll
        for (int r = 0; r < 4; r++) bvv[mf][r] = bias[co0 + mf * 16 + 4 * l4 + r];

    bf16* dst = (co0 < 128) ? xh : kk;
    const int cod = co0 & 127;
#pragma unroll
    for (int mf = 0; mf < 4; mf++) {
#pragma unroll
        for (int nf = 0; nf < 4; nf++) {
            int w = w0 + nf * 16 + l15;
            bf16x4 v;
#pragma unroll
            for (int r = 0; r < 4; r++) v[r] = (bf16)(acc[mf][nf][r] + bvv[mf][r]);
            *(bf16x4*)&dst[((size_t)(b * H_ + hG) * W_ + w) * C_ + cod + mf * 16 + 4 * l4] = v;
        }
        if (co0 < 128) {
#pragma unroll
            for (int r = 0; r < 4; r++) {
                float s = 4.f * bvv[mf][r];
#pragma unroll
                for (int nf = 0; nf < 4; nf++) s += acc[mf][nf][r];
                s += __shfl_xor(s, 1, 64);
                s += __shfl_xor(s, 2, 64);
                s += __shfl_xor(s, 4, 64);
                s += __shfl_xor(s, 8, 64);
                if (l15 == 0)
                    atomicAdd(&meansum[b * 128 + co0 + mf * 16 + 4 * l4 + r], s);
            }
        }
    }
}

// ---------------------------------------------------------------------------
// K2: gating (top-2 of 3; drop argmin, ties drop larger index)
// ---------------------------------------------------------------------------
__global__ void gate_kernel(const float* __restrict__ meansum,
                            const float* __restrict__ gw,
                            float* __restrict__ gate)
{
    int b = threadIdx.x;
    if (b >= 8) return;
    float l[3];
    for (int e = 0; e < 3; e++) {
        float s = 0.f;
        for (int c = 0; c < 128; c++) s += meansum[b * 128 + c] * gw[e * 128 + c];
        l[e] = s * (1.0f / 16384.0f);
    }
    float m = fmaxf(l[0], fmaxf(l[1], l[2]));
    float p0 = expf(l[0] - m), p1 = expf(l[1] - m), p2 = expf(l[2] - m);
    float s = p0 + p1 + p2;
    float w[3] = { p0 / s, p1 / s, p2 / s };
    int dm = 0;
    if (w[1] <= w[0]) dm = 1;
    if (w[2] <= w[dm]) dm = 2;
    for (int e = 0; e < 3; e++) gate[b * 3 + e] = (e == dm) ? 0.f : w[e];
}

// ---------------------------------------------------------------------------
// K3a/K3b: fem_b(0) -> [C][9-region] map
// ---------------------------------------------------------------------------
__global__ __launch_bounds__(128) void out2a_kernel(
    const float* __restrict__ c1b,
    const float* __restrict__ ew1, const float* __restrict__ eb1,
    const float* __restrict__ ew2, const float* __restrict__ eb2,
    float* __restrict__ sprod)
{
    const int e = blockIdx.x >> 7, c = blockIdx.x & 127;
    const int t = threadIdx.x;
    float xv = c1b[t], kv = c1b[128 + t];
    const float* w1 = ew1 + ((size_t)(e * 128 + c) * 128 + t) * 9;
    const float* w2 = ew2 + ((size_t)(e * 128 + c) * 128 + t) * 9;
    __shared__ float rA[9][128], rB[9][128];
#pragma unroll
    for (int tp = 0; tp < 9; tp++) { rA[tp][t] = xv * w1[tp]; rB[tp][t] = kv * w2[tp]; }
    __syncthreads();
    for (int s = 64; s > 0; s >>= 1) {
        if (t < s)
#pragma unroll
            for (int tp = 0; tp < 9; tp++) { rA[tp][t] += rA[tp][t + s]; rB[tp][t] += rB[tp][t + s]; }
        __syncthreads();
    }
    if (t < 9) {
        int rcl = t / 3, ccl = t % 3;
        float av = eb1[e * 128 + c], bv = eb2[e * 128 + c];
#pragma unroll
        for (int i = 0; i < 3; i++)
#pragma unroll
            for (int j = 0; j < 3; j++) {
                bool iok = (rcl == 1) || (rcl == 0 && i >= 1) || (rcl == 2 && i <= 1);
                bool jok = (ccl == 1) || (ccl == 0 && j >= 1) || (ccl == 2 && j <= 1);
                if (iok && jok) { av += rA[i * 3 + j][0]; bv += rB[i * 3 + j][0]; }
            }
        sprod[(size_t)(e * 128 + c) * 9 + t] = av * bv;
    }
}

__global__ __launch_bounds__(128) void out2b_kernel(
    const float* __restrict__ c1b, const float* __restrict__ gw,
    const float* __restrict__ sprod, const float* __restrict__ ew3,
    const float* __restrict__ eb3, float* __restrict__ out2map)
{
    const int c = blockIdx.x;
    const int t = threadIdx.x;
    __shared__ float red[27][128];
#pragma unroll
    for (int e = 0; e < 3; e++) {
        float wv = ew3[(size_t)(e * 128 + c) * 128 + t];
#pragma unroll
        for (int r = 0; r < 9; r++) red[e * 9 + r][t] = wv * sprod[(size_t)(e * 128 + t) * 9 + r];
    }
    __syncthreads();
    for (int s = 64; s > 0; s >>= 1) {
        if (t < s)
#pragma unroll
            for (int q = 0; q < 27; q++) red[q][t] += red[q][t + s];
        __syncthreads();
    }
    __shared__ float lsh[3];
    if (t < 3) {
        float s = 0.f;
        for (int cc = 0; cc < 128; cc++) s += c1b[cc] * gw[t * 128 + cc];
        lsh[t] = s;
    }
    __syncthreads();
    if (t == 0) {
        float l0 = lsh[0], l1 = lsh[1], l2 = lsh[2];
        float m = fmaxf(l0, fmaxf(l1, l2));
        float p0 = expf(l0 - m), p1 = expf(l1 - m), p2 = expf(l2 - m);
        float ssum = p0 + p1 + p2;
        float wv[3] = { p0 / ssum, p1 / ssum, p2 / ssum };
        int dm = 0;
        if (wv[1] <= wv[0]) dm = 1;
        if (wv[2] <= wv[dm]) dm = 2;
        wv[dm] = 0.f;
        for (int r = 0; r < 9; r++) {
            float o = c1b[c];
            for (int e = 0; e < 3; e++)
                o += wv[e] * (red[e * 9 + r][0] + eb3[e * 128 + c]);
            out2map[c * 9 + r] = o;
        }
    }
}

// ---------------------------------------------------------------------------
// K4: both experts per staged tile. X/K double-buffered (4 x 17408B);
// per cb: one vmcnt + barrier, then 288-MFMA barrier-free region (both convs,
// both experts), then restage behind one barrier. R4-proven tail + epilogue.
// ---------------------------------------------------------------------------
__global__ __launch_bounds__(512, 2) void expert_kernel(
    const bf16* __restrict__ xhp, const bf16* __restrict__ kkp,
    const bf16* __restrict__ we1, const float* __restrict__ eb1,
    const bf16* __restrict__ we2, const float* __restrict__ eb2,
    const bf16* __restrict__ w3, const float* __restrict__ eb3,
    const float* __restrict__ gate, const float* __restrict__ o2map,
    const float* __restrict__ x, float* __restrict__ out,
    const bf16* __restrict__ zbuf)
{
    const int bid = blockIdx.x;
    const int b = bid & 7, rp = (bid >> 3) & 63, pxh = bid >> 9;
    const int h0 = rp * 2, w0 = pxh * 64;
    const int t = threadIdx.x, lane = t & 63, ww = t >> 6;
    const int l15 = lane & 15, l4 = lane >> 4;
    const int rowL = ww & 1, co0 = (ww >> 1) * 32;
    __shared__ char sm[70656];
    char* X0 = sm;
    char* K0 = sm + 17408;
    char* X1 = sm + 34816;
    char* K1 = sm + 52224;
    char* dump = sm + 69632;

    float ga0 = gate[b * 3 + 0], ga1 = gate[b * 3 + 1], ga2 = gate[b * 3 + 2];
    int e0, e1; float w_e0, w_e1;
    if (ga0 > 0.f) { e0 = 0; w_e0 = ga0; if (ga1 > 0.f) { e1 = 1; w_e1 = ga1; } else { e1 = 2; w_e1 = ga2; } }
    else           { e0 = 1; w_e0 = ga1; e1 = 2; w_e1 = ga2; }

    f32x4 aa[2][2][4], ab[2][2][4];   // [expert][mf co][nf px]
#pragma unroll
    for (int pe = 0; pe < 2; pe++)
#pragma unroll
        for (int mf = 0; mf < 2; mf++)
#pragma unroll
            for (int nf = 0; nf < 4; nf++) {
                aa[pe][mf][nf] = (f32x4){0.f, 0.f, 0.f, 0.f};
                ab[pe][mf][nf] = (f32x4){0.f, 0.f, 0.f, 0.f};
            }

    stage_tile(xhp, zbuf, X0, dump, t, ww, b, h0, w0, 0);
    stage_tile(kkp, zbuf, K0, dump, t, ww, b, h0, w0, 0);
    stage_tile(xhp, zbuf, X1, dump, t, ww, b, h0, w0, 1);
    stage_tile(kkp, zbuf, K1, dump, t, ww, b, h0, w0, 1);

#pragma unroll
    for (int cb = 0; cb < 4; cb++) {
        if (cb < 3) { WAITVM6; } else { WAITVM0; }
        barrier_raw();
        const char* X = (cb & 1) ? X1 : X0;
        const char* K = (cb & 1) ? K1 : K0;

#pragma unroll 1
        for (int dy = 0; dy < 3; dy++) {
            const int row_h = rowL + dy;
#pragma unroll
            for (int dx = 0; dx < 3; dx++) {
                const int tap = dy * 3 + dx;
                int bofs[4];
#pragma unroll
                for (int nf = 0; nf < 4; nf++) {
                    int wl = nf * 16 + l15 + dx;
                    bofs[nf] = (row_h * 272 + wl * 4 + (l4 ^ ((wl >> 1) & 3))) * 16;
                }
                // conv_a: weights we1, image X
                bf16x8 a10[2], a11[2];
#pragma unroll
                for (int mf = 0; mf < 2; mf++) {
                    a10[mf] = *(const bf16x8*)&we1[(size_t)((e0 * 9 + tap) * 128 + co0 + mf * 16 + l15) * 128 + cb * 32 + l4 * 8];
                    a11[mf] = *(const bf16x8*)&we1[(size_t)((e1 * 9 + tap) * 128 + co0 + mf * 16 + l15) * 128 + cb * 32 + l4 * 8];
                }
#pragma unroll
                for (int nf = 0; nf < 4; nf++) {
                    bf16x8 bx = *(const bf16x8*)(X + bofs[nf]);
#pragma unroll
                    for (int mf = 0; mf < 2; mf++) {
                        aa[0][mf][nf] = __builtin_amdgcn_mfma_f32_16x16x32_bf16(a10[mf], bx, aa[0][mf][nf], 0, 0, 0);
                        aa[1][mf][nf] = __builtin_amdgcn_mfma_f32_16x16x32_bf16(a11[mf], bx, aa[1][mf][nf], 0, 0, 0);
                    }
                }
                // conv_b: weights we2, image K
                bf16x8 a20[2], a21[2];
#pragma unroll
                for (int mf = 0; mf < 2; mf++) {
                    a20[mf] = *(const bf16x8*)&we2[(size_t)((e0 * 9 + tap) * 128 + co0 + mf * 16 + l15) * 128 + cb * 32 + l4 * 8];
                    a21[mf] = *(const bf16x8*)&we2[(size_t)((e1 * 9 + tap) * 128 + co0 + mf * 16 + l15) * 128 + cb * 32 + l4 * 8];
                }
#pragma unroll
                for (int nf = 0; nf < 4; nf++) {
                    bf16x8 bk = *(const bf16x8*)(K + bofs[nf]);
#pragma unroll
                    for (int mf = 0; mf < 2; mf++) {
                        ab[0][mf][nf] = __builtin_amdgcn_mfma_f32_16x16x32_bf16(a20[mf], bk, ab[0][mf][nf], 0, 0, 0);
                        ab[1][mf][nf] = __builtin_amdgcn_mfma_f32_16x16x32_bf16(a21[mf], bk, ab[1][mf][nf], 0, 0, 0);
                    }
                }
            }
        }

        if (cb < 2) {
            barrier_raw();    // all waves done reading buf[cb&1] before restage
            stage_tile(xhp, zbuf, (cb & 1) ? X1 : X0, dump, t, ww, b, h0, w0, cb + 2);
            stage_tile(kkp, zbuf, (cb & 1) ? K1 : K0, dump, t, ww, b, h0, w0, cb + 2);
        }
    }
    barrier_raw();   // staging reads done block-wide before P overwrite

    // ---- tail (R4-proven): P per expert in LDS (aliases X0/K0), 1x1 GEMM ----
    f32x4 eoA[2][4], eoB[2][4];
#pragma unroll
    for (int mf = 0; mf < 2; mf++)
#pragma unroll
        for (int nf = 0; nf < 4; nf++) {
            eoA[mf][nf] = (f32x4){0.f, 0.f, 0.f, 0.f};
            eoB[mf][nf] = (f32x4){0.f, 0.f, 0.f, 0.f};
        }

#pragma unroll
    for (int pe = 0; pe < 2; pe++) {
        const int e = pe ? e1 : e0;
        const int ccb = co0 + 4 * l4;
        float b1v[2][4], b2v[2][4];
#pragma unroll
        for (int mf = 0; mf < 2; mf++)
#pragma unroll
            for (int r = 0; r < 4; r++) {
                b1v[mf][r] = eb1[e * 128 + ccb + mf * 16 + r];
                b2v[mf][r] = eb2[e * 128 + ccb + mf * 16 + r];
            }
#pragma unroll
        for (int mf = 0; mf < 2; mf++)
#pragma unroll
            for (int nf = 0; nf < 4; nf++) {
                int px = rowL * 64 + nf * 16 + l15;
                int cc = ccb + mf * 16;
                bf16x4 pv;
#pragma unroll
                for (int r = 0; r < 4; r++)
                    pv[r] = (bf16)((aa[pe][mf][nf][r] + b1v[mf][r]) * (ab[pe][mf][nf][r] + b2v[mf][r]));
                int byt = px * 256 + (((cc >> 3) ^ (px & 15)) * 16) + (cc & 7) * 2;
                *(bf16x4*)(sm + byt) = pv;
            }
        barrier_raw();

        // 1x1 GEMM over K=128 from P
#pragma unroll 1
        for (int ks = 0; ks < 4; ks++) {
            bf16x8 a3[2];
#pragma unroll
            for (int mf = 0; mf < 2; mf++)
                a3[mf] = *(const bf16x8*)&w3[(size_t)(e * 128 + co0 + mf * 16 + l15) * 128 + ks * 32 + l4 * 8];
#pragma unroll
            for (int nf = 0; nf < 4; nf++) {
                int px = rowL * 64 + nf * 16 + l15;
                int byt = px * 256 + (((ks * 4 + l4) ^ (px & 15)) * 16);
                bf16x8 bp = *(const bf16x8*)(sm + byt);
#pragma unroll
                for (int mf = 0; mf < 2; mf++) {
                    if (pe == 0)
                        eoA[mf][nf] = __builtin_amdgcn_mfma_f32_16x16x32_bf16(a3[mf], bp, eoA[mf][nf], 0, 0, 0);
                    else
                        eoB[mf][nf] = __builtin_amdgcn_mfma_f32_16x16x32_bf16(a3[mf], bp, eoB[mf][nf], 0, 0, 0);
                }
            }
        }
        barrier_raw();   // P region reused by next expert
    }

    // ---- epilogue (R4-proven): single coalesced write ----
    const int h = h0 + rowL;
    const int rcl = (h == 0) ? 0 : ((h == 127) ? 2 : 1);
#pragma unroll
    for (int mf = 0; mf < 2; mf++) {
        int cbase = co0 + mf * 16 + 4 * l4;
        float b30[4], b31[4];
#pragma unroll
        for (int r = 0; r < 4; r++) {
            b30[r] = eb3[e0 * 128 + cbase + r];
            b31[r] = eb3[e1 * 128 + cbase + r];
        }
#pragma unroll
        for (int nf = 0; nf < 4; nf++) {
            int w = w0 + nf * 16 + l15;
            bf16x4 xv = *(const bf16x4*)&xhp[((size_t)(b * H_ + h) * W_ + w) * C_ + cbase];
            int ccl = (w == 0) ? 0 : ((w == 127) ? 2 : 1);
#pragma unroll
            for (int r = 0; r < 4; r++) {
                size_t gi = ((size_t)(b * C_ + cbase + r) * H_ + h) * W_ + w;
                out[gi] = (float)xv[r] + x[gi] + o2map[(cbase + r) * 9 + rcl * 3 + ccl]
                        + w_e0 * (eoA[mf][nf][r] + b30[r])
                        + w_e1 * (eoB[mf][nf][r] + b31[r]);
            }
        }
    }
}

// ---------------------------------------------------------------------------
extern "C" void kernel_launch(void* const* d_in, const int* in_sizes, int n_in,
                              void* d_out, int out_size, void* d_ws, size_t ws_size,
                              hipStream_t stream)
{
    const float* x      = (const float*)d_in[0];
    const float* a_c1w  = (const float*)d_in[1];
    const float* a_c1b  = (const float*)d_in[2];
    const float* a_gw   = (const float*)d_in[3];
    const float* a_ew1  = (const float*)d_in[4];
    const float* a_eb1  = (const float*)d_in[5];
    const float* a_ew2  = (const float*)d_in[6];
    const float* a_eb2  = (const float*)d_in[7];
    const float* a_ew3  = (const float*)d_in[8];
    const float* a_eb3  = (const float*)d_in[9];
    const float* b_c1b  = (const float*)d_in[11];
    const float* b_gw   = (const float*)d_in[12];
    const float* b_ew1  = (const float*)d_in[13];
    const float* b_eb1  = (const float*)d_in[14];
    const float* b_ew2  = (const float*)d_in[15];
    const float* b_eb2  = (const float*)d_in[16];
    const float* b_ew3  = (const float*)d_in[17];
    const float* b_eb3  = (const float*)d_in[18];
    float* out = (float*)d_out;

    char* ws = (char*)d_ws;
    bf16*  xh      = (bf16*)(ws);                      // 33554432 B
    bf16*  kk      = (bf16*)(ws + 33554432);           // 33554432 B
    bf16*  wT1     = (bf16*)(ws + 67108864);           // 589824 B
    bf16*  wTe1    = (bf16*)(ws + 67698688);           // 884736 B
    bf16*  wTe2    = (bf16*)(ws + 68583424);           // 884736 B
    bf16*  wT3     = (bf16*)(ws + 69468160);           // 98304 B
    float* meansum = (float*)(ws + 69566464);          // 4096 B
    float* gate    = (float*)(ws + 69570560);          // 128 B
    float* o2map   = (float*)(ws + 69570688);          // 4608 B
    bf16*  zbuf    = (bf16*)(ws + 69575296);           // 256 B
    float* sprod   = (float*)(ws + 69575552);          // 13824 B

    bf16* xa = (bf16*)d_out;   // |x| NHWC bf16 scratch (overwritten last)

    hipMemsetAsync(ws + 69566464, 0, 4096, stream);        // meansum
    hipMemsetAsync(ws + 69575296, 0, 256, stream);         // zero buffer

    wprep1_kernel<<<(256 * 128 * 9 + 255) / 256, 256, 0, stream>>>(a_c1w, wT1);
    wprepE_kernel<<<(3 * 128 * 128 * 9 + 255) / 256, 256, 0, stream>>>(a_ew1, wTe1);
    wprepE_kernel<<<(3 * 128 * 128 * 9 + 255) / 256, 256, 0, stream>>>(a_ew2, wTe2);
    wprep3_kernel<<<(3 * 128 * 128 + 255) / 256, 256, 0, stream>>>(a_ew3, wT3);

    xpose_kernel<<<dim3(4, 128, 8), 256, 0, stream>>>(x, xa);

    conv1_kernel<<<1024, 512, 0, stream>>>(xa, wT1, a_c1b, xh, kk, meansum, zbuf);

    gate_kernel<<<1, 64, 0, stream>>>(meansum, a_gw, gate);
    out2a_kernel<<<384, 128, 0, stream>>>(b_c1b, b_ew1, b_eb1, b_ew2, b_eb2, sprod);
    out2b_kernel<<<128, 128, 0, stream>>>(b_c1b, b_gw, sprod, b_ew3, b_eb3, o2map);

    expert_kernel<<<1024, 512, 0, stream>>>(
        xh, kk, wTe1, a_eb1, wTe2, a_eb2, wT3, a_eb3, gate, o2map, x, out, zbuf);
}

// Round 7
// 317.641 us; speedup vs baseline: 2.1141x; 1.6954x over previous
//
#include <hip/hip_runtime.h>
#include <hip/hip_bf16.h>

#define B_ 8
#define C_ 128
#define H_ 128
#define W_ 128

typedef __bf16 bf16;
typedef __bf16 bf16x8 __attribute__((ext_vector_type(8)));
typedef __bf16 bf16x4 __attribute__((ext_vector_type(4)));
typedef float f32x4 __attribute__((ext_vector_type(4)));

#define GLD_LDS16(gsrc, ldsdst)                                                              \
    __builtin_amdgcn_global_load_lds((const __attribute__((address_space(1))) void*)(gsrc),  \
                                     (__attribute__((address_space(3))) void*)(ldsdst),      \
                                     16, 0, 0)

#define WAITVM0 asm volatile("s_waitcnt vmcnt(0)" ::: "memory")
#define WAITVM3 asm volatile("s_waitcnt vmcnt(3)" ::: "memory")
#define WAITVM6 asm volatile("s_waitcnt vmcnt(6)" ::: "memory")

__device__ __forceinline__ void barrier_raw() {
    __builtin_amdgcn_sched_barrier(0);
    __builtin_amdgcn_s_barrier();
    __builtin_amdgcn_sched_barrier(0);
}

// ---------------------------------------------------------------------------
// Weight prep: per-lane MFMA fragment order so every A-frag load is a single
// fully-coalesced 1KB burst (lane i reads base + i*16B).
// Fragment for lane (l4=lane>>4, l15=lane&15): co = cg*16 + l15,
// cc = cb*32 + l4*8 + j (j=0..7).
// ---------------------------------------------------------------------------
__global__ void wprep1_kernel(const float* __restrict__ w, bf16* __restrict__ o) {
    // a_c1w [256co][128cc][9tap] -> [cb4][tap9][cg16][lane64][8] bf16
    int i = blockIdx.x * 256 + threadIdx.x;
    if (i >= 256 * 128 * 9) return;
    int tap = i % 9, cc = (i / 9) % 128, co = i / (9 * 128);
    int cb = cc >> 5, l4 = (cc >> 3) & 3, j = cc & 7;
    int cg = co >> 4, l15 = co & 15;
    o[((size_t)((cb * 9 + tap) * 16 + cg) * 64 + l4 * 16 + l15) * 8 + j] = (bf16)w[i];
}

__global__ void wprepE_kernel(const float* __restrict__ w, bf16* __restrict__ o) {
    // ew [3][128co][128cc][9] -> [e][cb4][tap9][cg8][lane64][8] bf16
    int i = blockIdx.x * 256 + threadIdx.x;
    if (i >= 3 * 128 * 128 * 9) return;
    int tap = i % 9, cc = (i / 9) % 128, co = (i / (9 * 128)) % 128, e = i / (9 * 128 * 128);
    int cb = cc >> 5, l4 = (cc >> 3) & 3, j = cc & 7;
    int cg = co >> 4, l15 = co & 15;
    o[((size_t)(((e * 4 + cb) * 9 + tap) * 8 + cg) * 64 + l4 * 16 + l15) * 8 + j] = (bf16)w[i];
}

__global__ void wprep3_kernel(const float* __restrict__ w, bf16* __restrict__ o) {
    // ew3 [3][128co][128cc] -> [e][ks4][cg8][lane64][8] bf16
    int i = blockIdx.x * 256 + threadIdx.x;
    if (i >= 3 * 128 * 128) return;
    int cc = i % 128, co = (i / 128) % 128, e = i / (128 * 128);
    int ks = cc >> 5, l4 = (cc >> 3) & 3, j = cc & 7;
    int cg = co >> 4, l15 = co & 15;
    o[((size_t)((e * 4 + ks) * 8 + cg) * 64 + l4 * 16 + l15) * 8 + j] = (bf16)w[i];
}

// ---------------------------------------------------------------------------
// |x| NCHW fp32 -> NHWC bf16
// ---------------------------------------------------------------------------
__global__ __launch_bounds__(256) void xpose_kernel(const float* __restrict__ x,
                                                    bf16* __restrict__ xa)
{
    const int cblk = blockIdx.x, h = blockIdx.y, b = blockIdx.z;
    const int t = threadIdx.x;
    __shared__ float sx[32][133];
    for (int i = t; i < 32 * 128; i += 256) {
        int c = i >> 7, w = i & 127;
        sx[c][w] = fabsf(x[((size_t)(b * C_ + cblk * 32 + c) * H_ + h) * W_ + w]);
    }
    __syncthreads();
    for (int g = t; g < 512; g += 256) {
        int w = g >> 2, slot = g & 3;
        bf16x8 v;
#pragma unroll
        for (int j = 0; j < 8; j++) v[j] = (bf16)sx[slot * 8 + j][w];
        *(bf16x8*)&xa[((size_t)(b * H_ + h) * W_ + w) * C_ + cblk * 32 + slot * 8] = v;
    }
}

// ---------------------------------------------------------------------------
// Staging tile: logical [4 halo rows][66 w][32 cc] bf16.
// granule g = row*272 + w*4 + sp, slot = sp ^ ((w>>1)&3). 1088 granules.
// Every wave issues EXACTLY 3 global_load_lds per stage.
// ---------------------------------------------------------------------------
__device__ __forceinline__ void stage_tile(const bf16* __restrict__ base,
    const bf16* __restrict__ zbuf, char* dst, char* dump,
    int t, int ww, int b, int h0, int w0, int cb)
{
#pragma unroll
    for (int k = 0; k < 3; k++) {
        int g = t + k * 512;
        char* d = dst + (size_t)((t & 448) + k * 512) * 16;
        bool real = (k < 2) || (ww == 0);
        if (k == 2 && ww != 0) d = dump;
        const bf16* src = zbuf;
        if (real) {
            int row = g / 272, rem = g - row * 272;
            int w = rem >> 2, sp = rem & 3;
            int slot = sp ^ ((w >> 1) & 3);
            int hh = h0 + row - 1, gw = w0 + w - 1;
            if (rem < 264 && (unsigned)hh < 128u && (unsigned)gw < 128u)
                src = base + ((size_t)(b * H_ + hh) * W_ + gw) * C_ + cb * 32 + slot * 8;
        }
        GLD_LDS16(src, d);
    }
}

// ---------------------------------------------------------------------------
// K1: conv3x3(|x|)+bias -> xh/kk + gating sums.
// ---------------------------------------------------------------------------
__global__ __launch_bounds__(512, 2) void conv1_kernel(
    const bf16* __restrict__ xa, const bf16* __restrict__ wT1,
    const float* __restrict__ bias,
    bf16* __restrict__ xh, bf16* __restrict__ kk,
    float* __restrict__ meansum, const bf16* __restrict__ zbuf)
{
    const int bid = blockIdx.x;
    const int b = bid & 7, rp = (bid >> 3) & 63, pxh = bid >> 9;
    const int h0 = rp * 2, w0 = pxh * 64;
    const int t = threadIdx.x, lane = t & 63, ww = t >> 6;
    const int l15 = lane & 15, l4 = lane >> 4;
    const int rowL = ww & 1, co0 = (ww >> 1) * 64;
    __shared__ char sm[35840];
    char* B0 = sm;
    char* B1 = sm + 17408;
    char* dump = sm + 34816;

    f32x4 acc[4][4];
#pragma unroll
    for (int mf = 0; mf < 4; mf++)
#pragma unroll
        for (int nf = 0; nf < 4; nf++) acc[mf][nf] = (f32x4){0.f, 0.f, 0.f, 0.f};

    stage_tile(xa, zbuf, B0, dump, t, ww, b, h0, w0, 0);
    stage_tile(xa, zbuf, B1, dump, t, ww, b, h0, w0, 1);

#pragma unroll
    for (int cb = 0; cb < 4; cb++) {
        if (cb < 3) { WAITVM3; } else { WAITVM0; }
        barrier_raw();
        const char* buf = (cb & 1) ? B1 : B0;
#pragma unroll 1
        for (int dy = 0; dy < 3; dy++) {
            const int row_h = rowL + dy;
#pragma unroll
            for (int dx = 0; dx < 3; dx++) {
                const int tap = dy * 3 + dx;
                bf16x8 af[4];
#pragma unroll
                for (int mf = 0; mf < 4; mf++)
                    af[mf] = *(const bf16x8*)&wT1[((size_t)((cb * 9 + tap) * 16 + (ww >> 1) * 4 + mf) * 64 + lane) * 8];
                bf16x8 bv[4];
#pragma unroll
                for (int nf = 0; nf < 4; nf++) {
                    int wl = nf * 16 + l15 + dx;
                    int byt = (row_h * 272 + wl * 4 + (l4 ^ ((wl >> 1) & 3))) * 16;
                    bv[nf] = *(const bf16x8*)(buf + byt);
                }
#pragma unroll
                for (int mf = 0; mf < 4; mf++)
#pragma unroll
                    for (int nf = 0; nf < 4; nf++)
                        acc[mf][nf] = __builtin_amdgcn_mfma_f32_16x16x32_bf16(af[mf], bv[nf], acc[mf][nf], 0, 0, 0);
            }
        }
        if (cb < 2) {
            barrier_raw();
            stage_tile(xa, zbuf, (cb & 1) ? B1 : B0, dump, t, ww, b, h0, w0, cb + 2);
        }
    }

    const int hG = h0 + rowL;
    float bvv[4][4];
#pragma unroll
    for (int mf = 0; mf < 4; mf++)
#pragma unroll
        for (int r = 0; r < 4; r++) bvv[mf][r] = bias[co0 + mf * 16 + 4 * l4 + r];

    bf16* dst = (co0 < 128) ? xh : kk;
    const int cod = co0 & 127;
#pragma unroll
    for (int mf = 0; mf < 4; mf++) {
#pragma unroll
        for (int nf = 0; nf < 4; nf++) {
            int w = w0 + nf * 16 + l15;
            bf16x4 v;
#pragma unroll
            for (int r = 0; r < 4; r++) v[r] = (bf16)(acc[mf][nf][r] + bvv[mf][r]);
            *(bf16x4*)&dst[((size_t)(b * H_ + hG) * W_ + w) * C_ + cod + mf * 16 + 4 * l4] = v;
        }
        if (co0 < 128) {
#pragma unroll
            for (int r = 0; r < 4; r++) {
                float s = 4.f * bvv[mf][r];
#pragma unroll
                for (int nf = 0; nf < 4; nf++) s += acc[mf][nf][r];
                s += __shfl_xor(s, 1, 64);
                s += __shfl_xor(s, 2, 64);
                s += __shfl_xor(s, 4, 64);
                s += __shfl_xor(s, 8, 64);
                if (l15 == 0)
                    atomicAdd(&meansum[b * 128 + co0 + mf * 16 + 4 * l4 + r], s);
            }
        }
    }
}

// ---------------------------------------------------------------------------
// K2: gating (top-2 of 3; drop argmin, ties drop larger index)
// ---------------------------------------------------------------------------
__global__ void gate_kernel(const float* __restrict__ meansum,
                            const float* __restrict__ gw,
                            float* __restrict__ gate)
{
    int b = threadIdx.x;
    if (b >= 8) return;
    float l[3];
    for (int e = 0; e < 3; e++) {
        float s = 0.f;
        for (int c = 0; c < 128; c++) s += meansum[b * 128 + c] * gw[e * 128 + c];
        l[e] = s * (1.0f / 16384.0f);
    }
    float m = fmaxf(l[0], fmaxf(l[1], l[2]));
    float p0 = expf(l[0] - m), p1 = expf(l[1] - m), p2 = expf(l[2] - m);
    float s = p0 + p1 + p2;
    float w[3] = { p0 / s, p1 / s, p2 / s };
    int dm = 0;
    if (w[1] <= w[0]) dm = 1;
    if (w[2] <= w[dm]) dm = 2;
    for (int e = 0; e < 3; e++) gate[b * 3 + e] = (e == dm) ? 0.f : w[e];
}

// ---------------------------------------------------------------------------
// K3a/K3b: fem_b(0) -> [C][9-region] map
// ---------------------------------------------------------------------------
__global__ __launch_bounds__(128) void out2a_kernel(
    const float* __restrict__ c1b,
    const float* __restrict__ ew1, const float* __restrict__ eb1,
    const float* __restrict__ ew2, const float* __restrict__ eb2,
    float* __restrict__ sprod)
{
    const int e = blockIdx.x >> 7, c = blockIdx.x & 127;
    const int t = threadIdx.x;
    float xv = c1b[t], kv = c1b[128 + t];
    const float* w1 = ew1 + ((size_t)(e * 128 + c) * 128 + t) * 9;
    const float* w2 = ew2 + ((size_t)(e * 128 + c) * 128 + t) * 9;
    __shared__ float rA[9][128], rB[9][128];
#pragma unroll
    for (int tp = 0; tp < 9; tp++) { rA[tp][t] = xv * w1[tp]; rB[tp][t] = kv * w2[tp]; }
    __syncthreads();
    for (int s = 64; s > 0; s >>= 1) {
        if (t < s)
#pragma unroll
            for (int tp = 0; tp < 9; tp++) { rA[tp][t] += rA[tp][t + s]; rB[tp][t] += rB[tp][t + s]; }
        __syncthreads();
    }
    if (t < 9) {
        int rcl = t / 3, ccl = t % 3;
        float av = eb1[e * 128 + c], bv = eb2[e * 128 + c];
#pragma unroll
        for (int i = 0; i < 3; i++)
#pragma unroll
            for (int j = 0; j < 3; j++) {
                bool iok = (rcl == 1) || (rcl == 0 && i >= 1) || (rcl == 2 && i <= 1);
                bool jok = (ccl == 1) || (ccl == 0 && j >= 1) || (ccl == 2 && j <= 1);
                if (iok && jok) { av += rA[i * 3 + j][0]; bv += rB[i * 3 + j][0]; }
            }
        sprod[(size_t)(e * 128 + c) * 9 + t] = av * bv;
    }
}

__global__ __launch_bounds__(128) void out2b_kernel(
    const float* __restrict__ c1b, const float* __restrict__ gw,
    const float* __restrict__ sprod, const float* __restrict__ ew3,
    const float* __restrict__ eb3, float* __restrict__ out2map)
{
    const int c = blockIdx.x;
    const int t = threadIdx.x;
    __shared__ float red[27][128];
#pragma unroll
    for (int e = 0; e < 3; e++) {
        float wv = ew3[(size_t)(e * 128 + c) * 128 + t];
#pragma unroll
        for (int r = 0; r < 9; r++) red[e * 9 + r][t] = wv * sprod[(size_t)(e * 128 + t) * 9 + r];
    }
    __syncthreads();
    for (int s = 64; s > 0; s >>= 1) {
        if (t < s)
#pragma unroll
            for (int q = 0; q < 27; q++) red[q][t] += red[q][t + s];
        __syncthreads();
    }
    __shared__ float lsh[3];
    if (t < 3) {
        float s = 0.f;
        for (int cc = 0; cc < 128; cc++) s += c1b[cc] * gw[t * 128 + cc];
        lsh[t] = s;
    }
    __syncthreads();
    if (t == 0) {
        float l0 = lsh[0], l1 = lsh[1], l2 = lsh[2];
        float m = fmaxf(l0, fmaxf(l1, l2));
        float p0 = expf(l0 - m), p1 = expf(l1 - m), p2 = expf(l2 - m);
        float ssum = p0 + p1 + p2;
        float wv[3] = { p0 / ssum, p1 / ssum, p2 / ssum };
        int dm = 0;
        if (wv[1] <= wv[0]) dm = 1;
        if (wv[2] <= wv[dm]) dm = 2;
        wv[dm] = 0.f;
        for (int r = 0; r < 9; r++) {
            float o = c1b[c];
            for (int e = 0; e < 3; e++)
                o += wv[e] * (red[e * 9 + r][0] + eb3[e * 128 + c]);
            out2map[c * 9 + r] = o;
        }
    }
}

// ---------------------------------------------------------------------------
// K4: both experts per staged tile; coalesced per-lane weight fragments.
// ---------------------------------------------------------------------------
__global__ __launch_bounds__(512, 2) void expert_kernel(
    const bf16* __restrict__ xhp, const bf16* __restrict__ kkp,
    const bf16* __restrict__ we1, const float* __restrict__ eb1,
    const bf16* __restrict__ we2, const float* __restrict__ eb2,
    const bf16* __restrict__ w3, const float* __restrict__ eb3,
    const float* __restrict__ gate, const float* __restrict__ o2map,
    const float* __restrict__ x, float* __restrict__ out,
    const bf16* __restrict__ zbuf)
{
    const int bid = blockIdx.x;
    const int b = bid & 7, rp = (bid >> 3) & 63, pxh = bid >> 9;
    const int h0 = rp * 2, w0 = pxh * 64;
    const int t = threadIdx.x, lane = t & 63, ww = t >> 6;
    const int l15 = lane & 15, l4 = lane >> 4;
    const int rowL = ww & 1, co0 = (ww >> 1) * 32;
    const int cgb = (ww >> 1) * 2;   // co group base (16-co granules)
    __shared__ char sm[70656];
    char* X0 = sm;
    char* K0 = sm + 17408;
    char* X1 = sm + 34816;
    char* K1 = sm + 52224;
    char* dump = sm + 69632;

    float ga0 = gate[b * 3 + 0], ga1 = gate[b * 3 + 1], ga2 = gate[b * 3 + 2];
    int e0, e1; float w_e0, w_e1;
    if (ga0 > 0.f) { e0 = 0; w_e0 = ga0; if (ga1 > 0.f) { e1 = 1; w_e1 = ga1; } else { e1 = 2; w_e1 = ga2; } }
    else           { e0 = 1; w_e0 = ga1; e1 = 2; w_e1 = ga2; }

    f32x4 aa[2][2][4], ab[2][2][4];   // [expert][mf co][nf px]
#pragma unroll
    for (int pe = 0; pe < 2; pe++)
#pragma unroll
        for (int mf = 0; mf < 2; mf++)
#pragma unroll
            for (int nf = 0; nf < 4; nf++) {
                aa[pe][mf][nf] = (f32x4){0.f, 0.f, 0.f, 0.f};
                ab[pe][mf][nf] = (f32x4){0.f, 0.f, 0.f, 0.f};
            }

    stage_tile(xhp, zbuf, X0, dump, t, ww, b, h0, w0, 0);
    stage_tile(kkp, zbuf, K0, dump, t, ww, b, h0, w0, 0);
    stage_tile(xhp, zbuf, X1, dump, t, ww, b, h0, w0, 1);
    stage_tile(kkp, zbuf, K1, dump, t, ww, b, h0, w0, 1);

#pragma unroll
    for (int cb = 0; cb < 4; cb++) {
        if (cb < 3) { WAITVM6; } else { WAITVM0; }
        barrier_raw();
        const char* X = (cb & 1) ? X1 : X0;
        const char* K = (cb & 1) ? K1 : K0;

#pragma unroll 1
        for (int dy = 0; dy < 3; dy++) {
            const int row_h = rowL + dy;
#pragma unroll
            for (int dx = 0; dx < 3; dx++) {
                const int tap = dy * 3 + dx;
                int bofs[4];
#pragma unroll
                for (int nf = 0; nf < 4; nf++) {
                    int wl = nf * 16 + l15 + dx;
                    bofs[nf] = (row_h * 272 + wl * 4 + (l4 ^ ((wl >> 1) & 3))) * 16;
                }
                // coalesced per-lane fragment loads: base + lane*16B
                bf16x8 a10[2], a11[2];
#pragma unroll
                for (int mf = 0; mf < 2; mf++) {
                    a10[mf] = *(const bf16x8*)&we1[((size_t)(((e0 * 4 + cb) * 9 + tap) * 8 + cgb + mf) * 64 + lane) * 8];
                    a11[mf] = *(const bf16x8*)&we1[((size_t)(((e1 * 4 + cb) * 9 + tap) * 8 + cgb + mf) * 64 + lane) * 8];
                }
#pragma unroll
                for (int nf = 0; nf < 4; nf++) {
                    bf16x8 bx = *(const bf16x8*)(X + bofs[nf]);
#pragma unroll
                    for (int mf = 0; mf < 2; mf++) {
                        aa[0][mf][nf] = __builtin_amdgcn_mfma_f32_16x16x32_bf16(a10[mf], bx, aa[0][mf][nf], 0, 0, 0);
                        aa[1][mf][nf] = __builtin_amdgcn_mfma_f32_16x16x32_bf16(a11[mf], bx, aa[1][mf][nf], 0, 0, 0);
                    }
                }
                bf16x8 a20[2], a21[2];
#pragma unroll
                for (int mf = 0; mf < 2; mf++) {
                    a20[mf] = *(const bf16x8*)&we2[((size_t)(((e0 * 4 + cb) * 9 + tap) * 8 + cgb + mf) * 64 + lane) * 8];
                    a21[mf] = *(const bf16x8*)&we2[((size_t)(((e1 * 4 + cb) * 9 + tap) * 8 + cgb + mf) * 64 + lane) * 8];
                }
#pragma unroll
                for (int nf = 0; nf < 4; nf++) {
                    bf16x8 bk = *(const bf16x8*)(K + bofs[nf]);
#pragma unroll
                    for (int mf = 0; mf < 2; mf++) {
                        ab[0][mf][nf] = __builtin_amdgcn_mfma_f32_16x16x32_bf16(a20[mf], bk, ab[0][mf][nf], 0, 0, 0);
                        ab[1][mf][nf] = __builtin_amdgcn_mfma_f32_16x16x32_bf16(a21[mf], bk, ab[1][mf][nf], 0, 0, 0);
                    }
                }
            }
        }

        if (cb < 2) {
            barrier_raw();
            stage_tile(xhp, zbuf, (cb & 1) ? X1 : X0, dump, t, ww, b, h0, w0, cb + 2);
            stage_tile(kkp, zbuf, (cb & 1) ? K1 : K0, dump, t, ww, b, h0, w0, cb + 2);
        }
    }
    barrier_raw();

    // ---- tail: P per expert in LDS, 1x1 GEMM ----
    f32x4 eoA[2][4], eoB[2][4];
#pragma unroll
    for (int mf = 0; mf < 2; mf++)
#pragma unroll
        for (int nf = 0; nf < 4; nf++) {
            eoA[mf][nf] = (f32x4){0.f, 0.f, 0.f, 0.f};
            eoB[mf][nf] = (f32x4){0.f, 0.f, 0.f, 0.f};
        }

#pragma unroll
    for (int pe = 0; pe < 2; pe++) {
        const int e = pe ? e1 : e0;
        const int ccb = co0 + 4 * l4;
        float b1v[2][4], b2v[2][4];
#pragma unroll
        for (int mf = 0; mf < 2; mf++)
#pragma unroll
            for (int r = 0; r < 4; r++) {
                b1v[mf][r] = eb1[e * 128 + ccb + mf * 16 + r];
                b2v[mf][r] = eb2[e * 128 + ccb + mf * 16 + r];
            }
#pragma unroll
        for (int mf = 0; mf < 2; mf++)
#pragma unroll
            for (int nf = 0; nf < 4; nf++) {
                int px = rowL * 64 + nf * 16 + l15;
                int cc = ccb + mf * 16;
                bf16x4 pv;
#pragma unroll
                for (int r = 0; r < 4; r++)
                    pv[r] = (bf16)((aa[pe][mf][nf][r] + b1v[mf][r]) * (ab[pe][mf][nf][r] + b2v[mf][r]));
                int byt = px * 256 + (((cc >> 3) ^ (px & 15)) * 16) + (cc & 7) * 2;
                *(bf16x4*)(sm + byt) = pv;
            }
        barrier_raw();

#pragma unroll 1
        for (int ks = 0; ks < 4; ks++) {
            bf16x8 a3[2];
#pragma unroll
            for (int mf = 0; mf < 2; mf++)
                a3[mf] = *(const bf16x8*)&w3[((size_t)((e * 4 + ks) * 8 + cgb + mf) * 64 + lane) * 8];
#pragma unroll
            for (int nf = 0; nf < 4; nf++) {
                int px = rowL * 64 + nf * 16 + l15;
                int byt = px * 256 + (((ks * 4 + l4) ^ (px & 15)) * 16);
                bf16x8 bp = *(const bf16x8*)(sm + byt);
#pragma unroll
                for (int mf = 0; mf < 2; mf++) {
                    if (pe == 0)
                        eoA[mf][nf] = __builtin_amdgcn_mfma_f32_16x16x32_bf16(a3[mf], bp, eoA[mf][nf], 0, 0, 0);
                    else
                        eoB[mf][nf] = __builtin_amdgcn_mfma_f32_16x16x32_bf16(a3[mf], bp, eoB[mf][nf], 0, 0, 0);
                }
            }
        }
        barrier_raw();
    }

    // ---- epilogue: single coalesced write ----
    const int h = h0 + rowL;
    const int rcl = (h == 0) ? 0 : ((h == 127) ? 2 : 1);
#pragma unroll
    for (int mf = 0; mf < 2; mf++) {
        int cbase = co0 + mf * 16 + 4 * l4;
        float b30[4], b31[4];
#pragma unroll
        for (int r = 0; r < 4; r++) {
            b30[r] = eb3[e0 * 128 + cbase + r];
            b31[r] = eb3[e1 * 128 + cbase + r];
        }
#pragma unroll
        for (int nf = 0; nf < 4; nf++) {
            int w = w0 + nf * 16 + l15;
            bf16x4 xv = *(const bf16x4*)&xhp[((size_t)(b * H_ + h) * W_ + w) * C_ + cbase];
            int ccl = (w == 0) ? 0 : ((w == 127) ? 2 : 1);
#pragma unroll
            for (int r = 0; r < 4; r++) {
                size_t gi = ((size_t)(b * C_ + cbase + r) * H_ + h) * W_ + w;
                out[gi] = (float)xv[r] + x[gi] + o2map[(cbase + r) * 9 + rcl * 3 + ccl]
                        + w_e0 * (eoA[mf][nf][r] + b30[r])
                        + w_e1 * (eoB[mf][nf][r] + b31[r]);
            }
        }
    }
}

// ---------------------------------------------------------------------------
extern "C" void kernel_launch(void* const* d_in, const int* in_sizes, int n_in,
                              void* d_out, int out_size, void* d_ws, size_t ws_size,
                              hipStream_t stream)
{
    const float* x      = (const float*)d_in[0];
    const float* a_c1w  = (const float*)d_in[1];
    const float* a_c1b  = (const float*)d_in[2];
    const float* a_gw   = (const float*)d_in[3];
    const float* a_ew1  = (const float*)d_in[4];
    const float* a_eb1  = (const float*)d_in[5];
    const float* a_ew2  = (const float*)d_in[6];
    const float* a_eb2  = (const float*)d_in[7];
    const float* a_ew3  = (const float*)d_in[8];
    const float* a_eb3  = (const float*)d_in[9];
    const float* b_c1b  = (const float*)d_in[11];
    const float* b_gw   = (const float*)d_in[12];
    const float* b_ew1  = (const float*)d_in[13];
    const float* b_eb1  = (const float*)d_in[14];
    const float* b_ew2  = (const float*)d_in[15];
    const float* b_eb2  = (const float*)d_in[16];
    const float* b_ew3  = (const float*)d_in[17];
    const float* b_eb3  = (const float*)d_in[18];
    float* out = (float*)d_out;

    char* ws = (char*)d_ws;
    bf16*  xh      = (bf16*)(ws);                      // 33554432 B
    bf16*  kk      = (bf16*)(ws + 33554432);           // 33554432 B
    bf16*  wT1     = (bf16*)(ws + 67108864);           // 589824 B
    bf16*  wTe1    = (bf16*)(ws + 67698688);           // 884736 B
    bf16*  wTe2    = (bf16*)(ws + 68583424);           // 884736 B
    bf16*  wT3     = (bf16*)(ws + 69468160);           // 98304 B
    float* meansum = (float*)(ws + 69566464);          // 4096 B
    float* gate    = (float*)(ws + 69570560);          // 128 B
    float* o2map   = (float*)(ws + 69570688);          // 4608 B
    bf16*  zbuf    = (bf16*)(ws + 69575296);           // 256 B
    float* sprod   = (float*)(ws + 69575552);          // 13824 B

    bf16* xa = (bf16*)d_out;   // |x| NHWC bf16 scratch (overwritten last)

    hipMemsetAsync(ws + 69566464, 0, 4096, stream);        // meansum
    hipMemsetAsync(ws + 69575296, 0, 256, stream);         // zero buffer

    wprep1_kernel<<<(256 * 128 * 9 + 255) / 256, 256, 0, stream>>>(a_c1w, wT1);
    wprepE_kernel<<<(3 * 128 * 128 * 9 + 255) / 256, 256, 0, stream>>>(a_ew1, wTe1);
    wprepE_kernel<<<(3 * 128 * 128 * 9 + 255) / 256, 256, 0, stream>>>(a_ew2, wTe2);
    wprep3_kernel<<<(3 * 128 * 128 + 255) / 256, 256, 0, stream>>>(a_ew3, wT3);

    xpose_kernel<<<dim3(4, 128, 8), 256, 0, stream>>>(x, xa);

    conv1_kernel<<<1024, 512, 0, stream>>>(xa, wT1, a_c1b, xh, kk, meansum, zbuf);

    gate_kernel<<<1, 64, 0, stream>>>(meansum, a_gw, gate);
    out2a_kernel<<<384, 128, 0, stream>>>(b_c1b, b_ew1, b_eb1, b_ew2, b_eb2, sprod);
    out2b_kernel<<<128, 128, 0, stream>>>(b_c1b, b_gw, sprod, b_ew3, b_eb3, o2map);

    expert_kernel<<<1024, 512, 0, stream>>>(
        xh, kk, wTe1, a_eb1, wTe2, a_eb2, wT3, a_eb3, gate, o2map, x, out, zbuf);
}

// Round 8
// 311.284 us; speedup vs baseline: 2.1573x; 1.0204x over previous
//
#include <hip/hip_runtime.h>
#include <hip/hip_bf16.h>

#define B_ 8
#define C_ 128
#define H_ 128
#define W_ 128

typedef __bf16 bf16;
typedef __bf16 bf16x8 __attribute__((ext_vector_type(8)));
typedef __bf16 bf16x4 __attribute__((ext_vector_type(4)));
typedef float f32x4 __attribute__((ext_vector_type(4)));

#define GLD_LDS16(gsrc, ldsdst)                                                              \
    __builtin_amdgcn_global_load_lds((const __attribute__((address_space(1))) void*)(gsrc),  \
                                     (__attribute__((address_space(3))) void*)(ldsdst),      \
                                     16, 0, 0)

#define WAITVM0 asm volatile("s_waitcnt vmcnt(0)" ::: "memory")
#define WAITVM2 asm volatile("s_waitcnt vmcnt(2)" ::: "memory")
#define WAITVM4 asm volatile("s_waitcnt vmcnt(4)" ::: "memory")

__device__ __forceinline__ void barrier_raw() {
    __builtin_amdgcn_sched_barrier(0);
    __builtin_amdgcn_s_barrier();
    __builtin_amdgcn_sched_barrier(0);
}

// ---------------------------------------------------------------------------
// Weight prep: per-lane MFMA fragment order (lane i reads base + i*16B).
// Fragment for lane (l4=lane>>4, l15=lane&15): co = cg*16 + l15,
// cc = cb*32 + l4*8 + j.
// ---------------------------------------------------------------------------
__global__ void wprep1_kernel(const float* __restrict__ w, bf16* __restrict__ o) {
    // a_c1w [256co][128cc][9tap] -> [cb4][tap9][cg16][lane64][8] bf16
    int i = blockIdx.x * 256 + threadIdx.x;
    if (i >= 256 * 128 * 9) return;
    int tap = i % 9, cc = (i / 9) % 128, co = i / (9 * 128);
    int cb = cc >> 5, l4 = (cc >> 3) & 3, j = cc & 7;
    int cg = co >> 4, l15 = co & 15;
    o[((size_t)((cb * 9 + tap) * 16 + cg) * 64 + l4 * 16 + l15) * 8 + j] = (bf16)w[i];
}

__global__ void wprepE_kernel(const float* __restrict__ w, bf16* __restrict__ o) {
    // ew [3][128co][128cc][9] -> [e][cb4][tap9][cg8][lane64][8] bf16
    int i = blockIdx.x * 256 + threadIdx.x;
    if (i >= 3 * 128 * 128 * 9) return;
    int tap = i % 9, cc = (i / 9) % 128, co = (i / (9 * 128)) % 128, e = i / (9 * 128 * 128);
    int cb = cc >> 5, l4 = (cc >> 3) & 3, j = cc & 7;
    int cg = co >> 4, l15 = co & 15;
    o[((size_t)(((e * 4 + cb) * 9 + tap) * 8 + cg) * 64 + l4 * 16 + l15) * 8 + j] = (bf16)w[i];
}

__global__ void wprep3_kernel(const float* __restrict__ w, bf16* __restrict__ o) {
    // ew3 [3][128co][128cc] -> [e][ks4][cg8][lane64][8] bf16
    int i = blockIdx.x * 256 + threadIdx.x;
    if (i >= 3 * 128 * 128) return;
    int cc = i % 128, co = (i / 128) % 128, e = i / (128 * 128);
    int ks = cc >> 5, l4 = (cc >> 3) & 3, j = cc & 7;
    int cg = co >> 4, l15 = co & 15;
    o[((size_t)((e * 4 + ks) * 8 + cg) * 64 + l4 * 16 + l15) * 8 + j] = (bf16)w[i];
}

// ---------------------------------------------------------------------------
// |x| NCHW fp32 -> NHWC bf16
// ---------------------------------------------------------------------------
__global__ __launch_bounds__(256) void xpose_kernel(const float* __restrict__ x,
                                                    bf16* __restrict__ xa)
{
    const int cblk = blockIdx.x, h = blockIdx.y, b = blockIdx.z;
    const int t = threadIdx.x;
    __shared__ float sx[32][133];
    for (int i = t; i < 32 * 128; i += 256) {
        int c = i >> 7, w = i & 127;
        sx[c][w] = fabsf(x[((size_t)(b * C_ + cblk * 32 + c) * H_ + h) * W_ + w]);
    }
    __syncthreads();
    for (int g = t; g < 512; g += 256) {
        int w = g >> 2, slot = g & 3;
        bf16x8 v;
#pragma unroll
        for (int j = 0; j < 8; j++) v[j] = (bf16)sx[slot * 8 + j][w];
        *(bf16x8*)&xa[((size_t)(b * H_ + h) * W_ + w) * C_ + cblk * 32 + slot * 8] = v;
    }
}

// ---------------------------------------------------------------------------
// Staging tile: logical [3 halo rows][66 w][32 cc] bf16, granule
// g = row*264 + w*4 + sp, slot = sp ^ ((w>>1)&3). 792 real granules,
// buffer padded to 1024 (16384 B). Each thread issues exactly 2 loads.
// ---------------------------------------------------------------------------
__device__ __forceinline__ void stage3(const bf16* __restrict__ base,
    const bf16* __restrict__ zbuf, char* dst,
    int t, int b, int h, int w0, int cb)
{
#pragma unroll
    for (int k = 0; k < 2; k++) {
        int g = t + k * 512;
        char* d = dst + (size_t)((t & 448) + k * 512) * 16;
        const bf16* src = zbuf;
        int row = g / 264, rem = g - row * 264;
        int w = rem >> 2, sp = rem & 3;
        int slot = sp ^ ((w >> 1) & 3);
        int hh = h + row - 1, gw = w0 + w - 1;
        if (g < 792 && (unsigned)hh < 128u && (unsigned)gw < 128u)
            src = base + ((size_t)(b * H_ + hh) * W_ + gw) * C_ + cb * 32 + slot * 8;
        GLD_LDS16(src, d);
    }
}

// ---------------------------------------------------------------------------
// K1: conv3x3(|x|)+bias -> xh/kk + gating sums.
// Block = 1 row x 64 px x 256 co; 8 waves of 32 co (mf=2). 2 blocks/CU target.
// ---------------------------------------------------------------------------
__global__ __launch_bounds__(512, 4) void conv1_kernel(
    const bf16* __restrict__ xa, const bf16* __restrict__ wT1,
    const float* __restrict__ bias,
    bf16* __restrict__ xh, bf16* __restrict__ kk,
    float* __restrict__ meansum, const bf16* __restrict__ zbuf)
{
    const int bid = blockIdx.x;
    const int b = bid & 7, h = (bid >> 3) & 127, pxh = bid >> 10;
    const int w0 = pxh * 64;
    const int t = threadIdx.x, lane = t & 63, ww = t >> 6;
    const int l15 = lane & 15, l4 = lane >> 4;
    const int co0 = ww * 32;
    __shared__ char sm[32768];
    char* B0 = sm;
    char* B1 = sm + 16384;

    f32x4 acc[2][4];
#pragma unroll
    for (int mf = 0; mf < 2; mf++)
#pragma unroll
        for (int nf = 0; nf < 4; nf++) acc[mf][nf] = (f32x4){0.f, 0.f, 0.f, 0.f};

    stage3(xa, zbuf, B0, t, b, h, w0, 0);
    stage3(xa, zbuf, B1, t, b, h, w0, 1);

#pragma unroll
    for (int cb = 0; cb < 4; cb++) {
        if (cb < 3) { WAITVM2; } else { WAITVM0; }
        barrier_raw();
        const char* buf = (cb & 1) ? B1 : B0;
#pragma unroll 1
        for (int dy = 0; dy < 3; dy++) {
#pragma unroll
            for (int dx = 0; dx < 3; dx++) {
                const int tap = dy * 3 + dx;
                bf16x8 af[2];
#pragma unroll
                for (int mf = 0; mf < 2; mf++)
                    af[mf] = *(const bf16x8*)&wT1[(size_t)((cb * 9 + tap) * 16 + ww * 2 + mf) * 512 + lane * 8];
                bf16x8 bv[4];
#pragma unroll
                for (int nf = 0; nf < 4; nf++) {
                    int wl = nf * 16 + l15 + dx;
                    int byt = (dy * 264 + wl * 4 + (l4 ^ ((wl >> 1) & 3))) * 16;
                    bv[nf] = *(const bf16x8*)(buf + byt);
                }
#pragma unroll
                for (int mf = 0; mf < 2; mf++)
#pragma unroll
                    for (int nf = 0; nf < 4; nf++)
                        acc[mf][nf] = __builtin_amdgcn_mfma_f32_16x16x32_bf16(af[mf], bv[nf], acc[mf][nf], 0, 0, 0);
            }
        }
        if (cb < 2) {
            barrier_raw();
            stage3(xa, zbuf, (cb & 1) ? B1 : B0, t, b, h, w0, cb + 2);
        }
    }

    float bvv[2][4];
#pragma unroll
    for (int mf = 0; mf < 2; mf++)
#pragma unroll
        for (int r = 0; r < 4; r++) bvv[mf][r] = bias[co0 + mf * 16 + 4 * l4 + r];

    bf16* dst = (co0 < 128) ? xh : kk;
    const int cod = co0 & 127;
#pragma unroll
    for (int mf = 0; mf < 2; mf++) {
#pragma unroll
        for (int nf = 0; nf < 4; nf++) {
            int w = w0 + nf * 16 + l15;
            bf16x4 v;
#pragma unroll
            for (int r = 0; r < 4; r++) v[r] = (bf16)(acc[mf][nf][r] + bvv[mf][r]);
            *(bf16x4*)&dst[((size_t)(b * H_ + h) * W_ + w) * C_ + cod + mf * 16 + 4 * l4] = v;
        }
        if (co0 < 128) {
#pragma unroll
            for (int r = 0; r < 4; r++) {
                float s = 4.f * bvv[mf][r];
#pragma unroll
                for (int nf = 0; nf < 4; nf++) s += acc[mf][nf][r];
                s += __shfl_xor(s, 1, 64);
                s += __shfl_xor(s, 2, 64);
                s += __shfl_xor(s, 4, 64);
                s += __shfl_xor(s, 8, 64);
                if (l15 == 0)
                    atomicAdd(&meansum[b * 128 + co0 + mf * 16 + 4 * l4 + r], s);
            }
        }
    }
}

// ---------------------------------------------------------------------------
// K2: gating (top-2 of 3; drop argmin, ties drop larger index)
// ---------------------------------------------------------------------------
__global__ void gate_kernel(const float* __restrict__ meansum,
                            const float* __restrict__ gw,
                            float* __restrict__ gate)
{
    int b = threadIdx.x;
    if (b >= 8) return;
    float l[3];
    for (int e = 0; e < 3; e++) {
        float s = 0.f;
        for (int c = 0; c < 128; c++) s += meansum[b * 128 + c] * gw[e * 128 + c];
        l[e] = s * (1.0f / 16384.0f);
    }
    float m = fmaxf(l[0], fmaxf(l[1], l[2]));
    float p0 = expf(l[0] - m), p1 = expf(l[1] - m), p2 = expf(l[2] - m);
    float s = p0 + p1 + p2;
    float w[3] = { p0 / s, p1 / s, p2 / s };
    int dm = 0;
    if (w[1] <= w[0]) dm = 1;
    if (w[2] <= w[dm]) dm = 2;
    for (int e = 0; e < 3; e++) gate[b * 3 + e] = (e == dm) ? 0.f : w[e];
}

// ---------------------------------------------------------------------------
// K3a/K3b: fem_b(0) -> [C][9-region] map
// ---------------------------------------------------------------------------
__global__ __launch_bounds__(128) void out2a_kernel(
    const float* __restrict__ c1b,
    const float* __restrict__ ew1, const float* __restrict__ eb1,
    const float* __restrict__ ew2, const float* __restrict__ eb2,
    float* __restrict__ sprod)
{
    const int e = blockIdx.x >> 7, c = blockIdx.x & 127;
    const int t = threadIdx.x;
    float xv = c1b[t], kv = c1b[128 + t];
    const float* w1 = ew1 + ((size_t)(e * 128 + c) * 128 + t) * 9;
    const float* w2 = ew2 + ((size_t)(e * 128 + c) * 128 + t) * 9;
    __shared__ float rA[9][128], rB[9][128];
#pragma unroll
    for (int tp = 0; tp < 9; tp++) { rA[tp][t] = xv * w1[tp]; rB[tp][t] = kv * w2[tp]; }
    __syncthreads();
    for (int s = 64; s > 0; s >>= 1) {
        if (t < s)
#pragma unroll
            for (int tp = 0; tp < 9; tp++) { rA[tp][t] += rA[tp][t + s]; rB[tp][t] += rB[tp][t + s]; }
        __syncthreads();
    }
    if (t < 9) {
        int rcl = t / 3, ccl = t % 3;
        float av = eb1[e * 128 + c], bv = eb2[e * 128 + c];
#pragma unroll
        for (int i = 0; i < 3; i++)
#pragma unroll
            for (int j = 0; j < 3; j++) {
                bool iok = (rcl == 1) || (rcl == 0 && i >= 1) || (rcl == 2 && i <= 1);
                bool jok = (ccl == 1) || (ccl == 0 && j >= 1) || (ccl == 2 && j <= 1);
                if (iok && jok) { av += rA[i * 3 + j][0]; bv += rB[i * 3 + j][0]; }
            }
        sprod[(size_t)(e * 128 + c) * 9 + t] = av * bv;
    }
}

__global__ __launch_bounds__(128) void out2b_kernel(
    const float* __restrict__ c1b, const float* __restrict__ gw,
    const float* __restrict__ sprod, const float* __restrict__ ew3,
    const float* __restrict__ eb3, float* __restrict__ out2map)
{
    const int c = blockIdx.x;
    const int t = threadIdx.x;
    __shared__ float red[27][128];
#pragma unroll
    for (int e = 0; e < 3; e++) {
        float wv = ew3[(size_t)(e * 128 + c) * 128 + t];
#pragma unroll
        for (int r = 0; r < 9; r++) red[e * 9 + r][t] = wv * sprod[(size_t)(e * 128 + t) * 9 + r];
    }
    __syncthreads();
    for (int s = 64; s > 0; s >>= 1) {
        if (t < s)
#pragma unroll
            for (int q = 0; q < 27; q++) red[q][t] += red[q][t + s];
        __syncthreads();
    }
    __shared__ float lsh[3];
    if (t < 3) {
        float s = 0.f;
        for (int cc = 0; cc < 128; cc++) s += c1b[cc] * gw[t * 128 + cc];
        lsh[t] = s;
    }
    __syncthreads();
    if (t == 0) {
        float l0 = lsh[0], l1 = lsh[1], l2 = lsh[2];
        float m = fmaxf(l0, fmaxf(l1, l2));
        float p0 = expf(l0 - m), p1 = expf(l1 - m), p2 = expf(l2 - m);
        float ssum = p0 + p1 + p2;
        float wv[3] = { p0 / ssum, p1 / ssum, p2 / ssum };
        int dm = 0;
        if (wv[1] <= wv[0]) dm = 1;
        if (wv[2] <= wv[dm]) dm = 2;
        wv[dm] = 0.f;
        for (int r = 0; r < 9; r++) {
            float o = c1b[c];
            for (int e = 0; e < 3; e++)
                o += wv[e] * (red[e * 9 + r][0] + eb3[e * 128 + c]);
            out2map[c * 9 + r] = o;
        }
    }
}

// ---------------------------------------------------------------------------
// K4: both experts. Block = 1 row x 64 px x 128 co; 8 waves of 16 co.
// acc = 64 regs -> 2 blocks/CU. P (64px x 128cc) aliases X0 region.
// ---------------------------------------------------------------------------
__global__ __launch_bounds__(512, 4) void expert_kernel(
    const bf16* __restrict__ xhp, const bf16* __restrict__ kkp,
    const bf16* __restrict__ we1, const float* __restrict__ eb1,
    const bf16* __restrict__ we2, const float* __restrict__ eb2,
    const bf16* __restrict__ w3, const float* __restrict__ eb3,
    const float* __restrict__ gate, const float* __restrict__ o2map,
    const float* __restrict__ x, float* __restrict__ out,
    const bf16* __restrict__ zbuf)
{
    const int bid = blockIdx.x;
    const int b = bid & 7, h = (bid >> 3) & 127, pxh = bid >> 10;
    const int w0 = pxh * 64;
    const int t = threadIdx.x, lane = t & 63, ww = t >> 6;
    const int l15 = lane & 15, l4 = lane >> 4;
    __shared__ char sm[65536];
    char* X0 = sm;
    char* K0 = sm + 16384;
    char* X1 = sm + 32768;
    char* K1 = sm + 49152;

    float ga0 = gate[b * 3 + 0], ga1 = gate[b * 3 + 1], ga2 = gate[b * 3 + 2];
    int e0, e1; float w_e0, w_e1;
    if (ga0 > 0.f) { e0 = 0; w_e0 = ga0; if (ga1 > 0.f) { e1 = 1; w_e1 = ga1; } else { e1 = 2; w_e1 = ga2; } }
    else           { e0 = 1; w_e0 = ga1; e1 = 2; w_e1 = ga2; }

    f32x4 aa[2][4], ab[2][4];   // [expert][nf]
#pragma unroll
    for (int pe = 0; pe < 2; pe++)
#pragma unroll
        for (int nf = 0; nf < 4; nf++) {
            aa[pe][nf] = (f32x4){0.f, 0.f, 0.f, 0.f};
            ab[pe][nf] = (f32x4){0.f, 0.f, 0.f, 0.f};
        }

    stage3(xhp, zbuf, X0, t, b, h, w0, 0);
    stage3(kkp, zbuf, K0, t, b, h, w0, 0);
    stage3(xhp, zbuf, X1, t, b, h, w0, 1);
    stage3(kkp, zbuf, K1, t, b, h, w0, 1);

#pragma unroll
    for (int cb = 0; cb < 4; cb++) {
        if (cb < 3) { WAITVM4; } else { WAITVM0; }
        barrier_raw();
        const char* X = (cb & 1) ? X1 : X0;
        const char* K = (cb & 1) ? K1 : K0;

#pragma unroll 1
        for (int dy = 0; dy < 3; dy++) {
#pragma unroll
            for (int dx = 0; dx < 3; dx++) {
                const int tap = dy * 3 + dx;
                int bofs[4];
#pragma unroll
                for (int nf = 0; nf < 4; nf++) {
                    int wl = nf * 16 + l15 + dx;
                    bofs[nf] = (dy * 264 + wl * 4 + (l4 ^ ((wl >> 1) & 3))) * 16;
                }
                bf16x8 a10, a11;
                a10 = *(const bf16x8*)&we1[(size_t)(((e0 * 4 + cb) * 9 + tap) * 8 + ww) * 512 + lane * 8];
                a11 = *(const bf16x8*)&we1[(size_t)(((e1 * 4 + cb) * 9 + tap) * 8 + ww) * 512 + lane * 8];
#pragma unroll
                for (int nf = 0; nf < 4; nf++) {
                    bf16x8 bx = *(const bf16x8*)(X + bofs[nf]);
                    aa[0][nf] = __builtin_amdgcn_mfma_f32_16x16x32_bf16(a10, bx, aa[0][nf], 0, 0, 0);
                    aa[1][nf] = __builtin_amdgcn_mfma_f32_16x16x32_bf16(a11, bx, aa[1][nf], 0, 0, 0);
                }
                bf16x8 a20, a21;
                a20 = *(const bf16x8*)&we2[(size_t)(((e0 * 4 + cb) * 9 + tap) * 8 + ww) * 512 + lane * 8];
                a21 = *(const bf16x8*)&we2[(size_t)(((e1 * 4 + cb) * 9 + tap) * 8 + ww) * 512 + lane * 8];
#pragma unroll
                for (int nf = 0; nf < 4; nf++) {
                    bf16x8 bk = *(const bf16x8*)(K + bofs[nf]);
                    ab[0][nf] = __builtin_amdgcn_mfma_f32_16x16x32_bf16(a20, bk, ab[0][nf], 0, 0, 0);
                    ab[1][nf] = __builtin_amdgcn_mfma_f32_16x16x32_bf16(a21, bk, ab[1][nf], 0, 0, 0);
                }
            }
        }

        if (cb < 2) {
            barrier_raw();
            stage3(xhp, zbuf, (cb & 1) ? X1 : X0, t, b, h, w0, cb + 2);
            stage3(kkp, zbuf, (cb & 1) ? K1 : K0, t, b, h, w0, cb + 2);
        }
    }
    // cb=3 used X1/K1 (sm+32768..); P writes go to sm[0..16384) = X0, whose
    // last reads (cb=2) completed before cb=3's entry barrier -> no barrier here.

    f32x4 eoA[4], eoB[4];
#pragma unroll
    for (int nf = 0; nf < 4; nf++) {
        eoA[nf] = (f32x4){0.f, 0.f, 0.f, 0.f};
        eoB[nf] = (f32x4){0.f, 0.f, 0.f, 0.f};
    }

#pragma unroll
    for (int pe = 0; pe < 2; pe++) {
        const int e = pe ? e1 : e0;
        const int ccb = ww * 16 + 4 * l4;   // cc slice of P this wave produces
        float b1v[4], b2v[4];
#pragma unroll
        for (int r = 0; r < 4; r++) {
            b1v[r] = eb1[e * 128 + ccb + r];
            b2v[r] = eb2[e * 128 + ccb + r];
        }
#pragma unroll
        for (int nf = 0; nf < 4; nf++) {
            int px = nf * 16 + l15;
            bf16x4 pv;
#pragma unroll
            for (int r = 0; r < 4; r++)
                pv[r] = (bf16)((aa[pe][nf][r] + b1v[r]) * (ab[pe][nf][r] + b2v[r]));
            int byt = px * 256 + (((ccb >> 3) ^ (px & 15)) * 16) + (ccb & 7) * 2;
            *(bf16x4*)(sm + byt) = pv;
        }
        barrier_raw();

#pragma unroll 1
        for (int ks = 0; ks < 4; ks++) {
            bf16x8 a3 = *(const bf16x8*)&w3[(size_t)((e * 4 + ks) * 8 + ww) * 512 + lane * 8];
#pragma unroll
            for (int nf = 0; nf < 4; nf++) {
                int px = nf * 16 + l15;
                int byt = px * 256 + (((ks * 4 + l4) ^ (px & 15)) * 16);
                bf16x8 bp = *(const bf16x8*)(sm + byt);
                if (pe == 0)
                    eoA[nf] = __builtin_amdgcn_mfma_f32_16x16x32_bf16(a3, bp, eoA[nf], 0, 0, 0);
                else
                    eoB[nf] = __builtin_amdgcn_mfma_f32_16x16x32_bf16(a3, bp, eoB[nf], 0, 0, 0);
            }
        }
        barrier_raw();   // P region reused by next expert
    }

    // ---- epilogue: single coalesced write ----
    const int rcl = (h == 0) ? 0 : ((h == 127) ? 2 : 1);
    const int cbase = ww * 16 + 4 * l4;
    float b30[4], b31[4];
#pragma unroll
    for (int r = 0; r < 4; r++) {
        b30[r] = eb3[e0 * 128 + cbase + r];
        b31[r] = eb3[e1 * 128 + cbase + r];
    }
#pragma unroll
    for (int nf = 0; nf < 4; nf++) {
        int w = w0 + nf * 16 + l15;
        bf16x4 xv = *(const bf16x4*)&xhp[((size_t)(b * H_ + h) * W_ + w) * C_ + cbase];
        int ccl = (w == 0) ? 0 : ((w == 127) ? 2 : 1);
#pragma unroll
        for (int r = 0; r < 4; r++) {
            size_t gi = ((size_t)(b * C_ + cbase + r) * H_ + h) * W_ + w;
            out[gi] = (float)xv[r] + x[gi] + o2map[(cbase + r) * 9 + rcl * 3 + ccl]
                    + w_e0 * (eoA[nf][r] + b30[r])
                    + w_e1 * (eoB[nf][r] + b31[r]);
        }
    }
}

// ---------------------------------------------------------------------------
extern "C" void kernel_launch(void* const* d_in, const int* in_sizes, int n_in,
                              void* d_out, int out_size, void* d_ws, size_t ws_size,
                              hipStream_t stream)
{
    const float* x      = (const float*)d_in[0];
    const float* a_c1w  = (const float*)d_in[1];
    const float* a_c1b  = (const float*)d_in[2];
    const float* a_gw   = (const float*)d_in[3];
    const float* a_ew1  = (const float*)d_in[4];
    const float* a_eb1  = (const float*)d_in[5];
    const float* a_ew2  = (const float*)d_in[6];
    const float* a_eb2  = (const float*)d_in[7];
    const float* a_ew3  = (const float*)d_in[8];
    const float* a_eb3  = (const float*)d_in[9];
    const float* b_c1b  = (const float*)d_in[11];
    const float* b_gw   = (const float*)d_in[12];
    const float* b_ew1  = (const float*)d_in[13];
    const float* b_eb1  = (const float*)d_in[14];
    const float* b_ew2  = (const float*)d_in[15];
    const float* b_eb2  = (const float*)d_in[16];
    const float* b_ew3  = (const float*)d_in[17];
    const float* b_eb3  = (const float*)d_in[18];
    float* out = (float*)d_out;

    char* ws = (char*)d_ws;
    bf16*  xh      = (bf16*)(ws);                      // 33554432 B
    bf16*  kk      = (bf16*)(ws + 33554432);           // 33554432 B
    bf16*  wT1     = (bf16*)(ws + 67108864);           // 589824 B
    bf16*  wTe1    = (bf16*)(ws + 67698688);           // 884736 B
    bf16*  wTe2    = (bf16*)(ws + 68583424);           // 884736 B
    bf16*  wT3     = (bf16*)(ws + 69468160);           // 98304 B
    float* meansum = (float*)(ws + 69566464);          // 4096 B
    float* gate    = (float*)(ws + 69570560);          // 128 B
    float* o2map   = (float*)(ws + 69570688);          // 4608 B
    bf16*  zbuf    = (bf16*)(ws + 69575296);           // 256 B
    float* sprod   = (float*)(ws + 69575552);          // 13824 B

    bf16* xa = (bf16*)d_out;   // |x| NHWC bf16 scratch (overwritten last)

    hipMemsetAsync(ws + 69566464, 0, 4096, stream);        // meansum
    hipMemsetAsync(ws + 69575296, 0, 256, stream);         // zero buffer

    wprep1_kernel<<<(256 * 128 * 9 + 255) / 256, 256, 0, stream>>>(a_c1w, wT1);
    wprepE_kernel<<<(3 * 128 * 128 * 9 + 255) / 256, 256, 0, stream>>>(a_ew1, wTe1);
    wprepE_kernel<<<(3 * 128 * 128 * 9 + 255) / 256, 256, 0, stream>>>(a_ew2, wTe2);
    wprep3_kernel<<<(3 * 128 * 128 + 255) / 256, 256, 0, stream>>>(a_ew3, wT3);

    xpose_kernel<<<dim3(4, 128, 8), 256, 0, stream>>>(x, xa);

    conv1_kernel<<<2048, 512, 0, stream>>>(xa, wT1, a_c1b, xh, kk, meansum, zbuf);

    gate_kernel<<<1, 64, 0, stream>>>(meansum, a_gw, gate);
    out2a_kernel<<<384, 128, 0, stream>>>(b_c1b, b_ew1, b_eb1, b_ew2, b_eb2, sprod);
    out2b_kernel<<<128, 128, 0, stream>>>(b_c1b, b_gw, sprod, b_ew3, b_eb3, o2map);

    expert_kernel<<<2048, 512, 0, stream>>>(
        xh, kk, wTe1, a_eb1, wTe2, a_eb2, wT3, a_eb3, gate, o2map, x, out, zbuf);
}